// Round 7
// baseline (6161.486 us; speedup 1.0000x reference)
//
#include <hip/hip_runtime.h>
#include <cstdint>

#define S_TOT 15795
#define B_SZ 2
#define NQ 80
#define XSPLIT 64
#define XCHUNK 256
#define MP 31616          // 31590 padded to multiple of 128

typedef __attribute__((ext_vector_type(8))) short short8;
typedef __attribute__((ext_vector_type(4))) float f32x4;

__device__ __forceinline__ unsigned short f2bf(float f) {
    unsigned u = __float_as_uint(f);
    unsigned r = u + 0x7fffu + ((u >> 16) & 1u);
    return (unsigned short)(r >> 16);
}
__device__ __forceinline__ float bf2f(unsigned short u) {
    return __uint_as_float((unsigned)u << 16);
}

// ---------------------------------------------------------------------------
__global__ __launch_bounds__(256)
void cast_bf16_kernel(const float* __restrict__ x, unsigned short* __restrict__ o, int n4)
{
    int i = blockIdx.x * 256 + threadIdx.x;
    if (i < n4) {
        float4 v = ((const float4*)x)[i];
        ushort4 r;
        r.x = f2bf(v.x); r.y = f2bf(v.y); r.z = f2bf(v.z); r.w = f2bf(v.w);
        ((ushort4*)o)[i] = r;
    }
}

// elementwise add, fp32 out
__global__ __launch_bounds__(256)
void add_kernel(const float* __restrict__ a, const float* __restrict__ b,
                float* __restrict__ o, int n4)
{
    int i = blockIdx.x * 256 + threadIdx.x;
    if (i < n4) {
        float4 av = ((const float4*)a)[i];
        float4 bv = ((const float4*)b)[i];
        float4 ov;
        ov.x = av.x + bv.x; ov.y = av.y + bv.y;
        ov.z = av.z + bv.z; ov.w = av.w + bv.w;
        ((float4*)o)[i] = ov;
    }
}

// elementwise add, bf16 out
__global__ __launch_bounds__(256)
void add_bf16_kernel(const float* __restrict__ a, const float* __restrict__ b,
                     unsigned short* __restrict__ o, int n4)
{
    int i = blockIdx.x * 256 + threadIdx.x;
    if (i < n4) {
        float4 av = ((const float4*)a)[i];
        float4 bv = ((const float4*)b)[i];
        ushort4 r;
        r.x = f2bf(av.x + bv.x); r.y = f2bf(av.y + bv.y);
        r.z = f2bf(av.z + bv.z); r.w = f2bf(av.w + bv.w);
        ((ushort4*)o)[i] = r;
    }
}

// ---------------------------------------------------------------------------
// pure-bf16 MFMA GEMM, register-staged DOUBLE-BUFFERED LDS (1 barrier/K-step).
// Y[M,N] = A[M,K](bf16) @ B[N,K](bf16)^T + bias.
// mode 0: fp32 out; 1: relu + bf16 out; 2: bf16 out (no relu).
// A readable to round-up-128(M) rows; N%128==0, K%32==0.
__global__ __launch_bounds__(256)
void gemm_bf16_kernel(const unsigned short* __restrict__ A,
                      const unsigned short* __restrict__ B,
                      const float* __restrict__ bias, void* __restrict__ Yv,
                      int M, int N, int K, int mode)
{
    __shared__ unsigned short As[2][128 * 32];
    __shared__ unsigned short Bs[2][128 * 32];
    const int t = threadIdx.x;
    const int wave = t >> 6, lane = t & 63;
    const int quad = lane >> 4, l16 = lane & 15;
    const int bm0 = blockIdx.y * 128;
    const int bn0 = blockIdx.x * 128;
    const int wm = (wave & 1) * 64;
    const int wn = (wave >> 1) * 64;
    const int srow = t >> 2;          // 0..63
    const int scol = (t & 3) * 8;     // 0,8,16,24

    f32x4 acc[4][4] = {};

    const unsigned short* pa0 = A + (size_t)(bm0 + srow) * K + scol;
    const unsigned short* pa1 = pa0 + (size_t)64 * K;
    const unsigned short* pb0 = B + (size_t)(bn0 + srow) * K + scol;
    const unsigned short* pb1 = pb0 + (size_t)64 * K;

    const int nk = K / 32;
    short8 a0 = *(const short8*)(pa0);
    short8 a1 = *(const short8*)(pa1);
    short8 b0 = *(const short8*)(pb0);
    short8 b1 = *(const short8*)(pb1);
    *(short8*)&As[0][srow * 32 + scol] = a0;
    *(short8*)&As[0][(srow + 64) * 32 + scol] = a1;
    *(short8*)&Bs[0][srow * 32 + scol] = b0;
    *(short8*)&Bs[0][(srow + 64) * 32 + scol] = b1;
    __syncthreads();

    for (int kb = 0; kb < nk; ++kb) {
        const int cur = kb & 1, nxt = cur ^ 1;
        const bool more = (kb + 1) < nk;
        if (more) {
            const int k0 = (kb + 1) * 32;
            a0 = *(const short8*)(pa0 + k0);
            a1 = *(const short8*)(pa1 + k0);
            b0 = *(const short8*)(pb0 + k0);
            b1 = *(const short8*)(pb1 + k0);
        }

        short8 af[4], bf[4];
        #pragma unroll
        for (int im = 0; im < 4; ++im)
            af[im] = *(const short8*)&As[cur][(wm + im * 16 + l16) * 32 + quad * 8];
        #pragma unroll
        for (int in = 0; in < 4; ++in)
            bf[in] = *(const short8*)&Bs[cur][(wn + in * 16 + l16) * 32 + quad * 8];
        #pragma unroll
        for (int im = 0; im < 4; ++im)
            #pragma unroll
            for (int in = 0; in < 4; ++in)
                acc[im][in] = __builtin_amdgcn_mfma_f32_16x16x32_bf16(
                    af[im], bf[in], acc[im][in], 0, 0, 0);

        if (more) {
            *(short8*)&As[nxt][srow * 32 + scol] = a0;
            *(short8*)&As[nxt][(srow + 64) * 32 + scol] = a1;
            *(short8*)&Bs[nxt][srow * 32 + scol] = b0;
            *(short8*)&Bs[nxt][(srow + 64) * 32 + scol] = b1;
        }
        __syncthreads();
    }

    // C/D: row = quad*4 + reg, col = l16
    #pragma unroll
    for (int im = 0; im < 4; ++im) {
        const int gm0 = bm0 + wm + im * 16 + quad * 4;
        #pragma unroll
        for (int in = 0; in < 4; ++in) {
            const int gn = bn0 + wn + in * 16 + l16;
            const float bv = bias[gn];
            #pragma unroll
            for (int r = 0; r < 4; ++r) {
                int row = gm0 + r;
                if (row < M) {
                    float o = acc[im][in][r] + bv;
                    if (mode == 0) {
                        ((float*)Yv)[(size_t)row * N + gn] = o;
                    } else {
                        if (mode == 1) o = fmaxf(o, 0.f);
                        ((unsigned short*)Yv)[(size_t)row * N + gn] = f2bf(o);
                    }
                }
            }
        }
    }
}

// ---------------------------------------------------------------------------
// fp32 GEMM for small decoder matrices. K%16==0, N%64==0.
__global__ __launch_bounds__(256)
void gemm_bias_kernel(const float* __restrict__ X, const float* __restrict__ W,
                      const float* __restrict__ bias, float* __restrict__ Y,
                      int M, int N, int K, int relu)
{
    __shared__ float Xs[16][68];
    __shared__ float Ws[16][68];
    const int bm0 = blockIdx.y * 64;
    const int bn0 = blockIdx.x * 64;
    const int t = threadIdx.x;
    const int tx = t & 15, ty = t >> 4;
    const int lr = t >> 2;
    const int lk = (t & 3) << 2;
    float acc[4][4] = {};
    const int xr = bm0 + lr;
    const int wr = bn0 + lr;
    const float* xp = X + (size_t)xr * K + lk;
    const float* wp = W + (size_t)wr * K + lk;
    for (int k0 = 0; k0 < K; k0 += 16) {
        float4 xv = make_float4(0.f, 0.f, 0.f, 0.f);
        if (xr < M) xv = *(const float4*)(xp + k0);
        float4 wv = make_float4(0.f, 0.f, 0.f, 0.f);
        if (wr < N) wv = *(const float4*)(wp + k0);
        Xs[lk + 0][lr] = xv.x; Xs[lk + 1][lr] = xv.y;
        Xs[lk + 2][lr] = xv.z; Xs[lk + 3][lr] = xv.w;
        Ws[lk + 0][lr] = wv.x; Ws[lk + 1][lr] = wv.y;
        Ws[lk + 2][lr] = wv.z; Ws[lk + 3][lr] = wv.w;
        __syncthreads();
        #pragma unroll
        for (int k = 0; k < 16; ++k) {
            float a0 = Xs[k][ty * 4 + 0], a1 = Xs[k][ty * 4 + 1];
            float a2 = Xs[k][ty * 4 + 2], a3 = Xs[k][ty * 4 + 3];
            float b0 = Ws[k][tx * 4 + 0], b1 = Ws[k][tx * 4 + 1];
            float b2 = Ws[k][tx * 4 + 2], b3 = Ws[k][tx * 4 + 3];
            acc[0][0] += a0 * b0; acc[0][1] += a0 * b1; acc[0][2] += a0 * b2; acc[0][3] += a0 * b3;
            acc[1][0] += a1 * b0; acc[1][1] += a1 * b1; acc[1][2] += a1 * b2; acc[1][3] += a1 * b3;
            acc[2][0] += a2 * b0; acc[2][1] += a2 * b1; acc[2][2] += a2 * b2; acc[2][3] += a2 * b3;
            acc[3][0] += a3 * b0; acc[3][1] += a3 * b1; acc[3][2] += a3 * b2; acc[3][3] += a3 * b3;
        }
        __syncthreads();
    }
    const int c0 = bn0 + tx * 4;
    float4 bv = *(const float4*)(bias + c0);
    #pragma unroll
    for (int i = 0; i < 4; ++i) {
        int r = bm0 + ty * 4 + i;
        if (r >= M) continue;
        float4 o;
        o.x = acc[i][0] + bv.x; o.y = acc[i][1] + bv.y;
        o.z = acc[i][2] + bv.z; o.w = acc[i][3] + bv.w;
        if (relu) {
            o.x = fmaxf(o.x, 0.f); o.y = fmaxf(o.y, 0.f);
            o.z = fmaxf(o.z, 0.f); o.w = fmaxf(o.w, 0.f);
        }
        *(float4*)(Y + (size_t)r * N + c0) = o;
    }
}

// ---------------------------------------------------------------------------
// LayerNorm(X + R)*g + b -> fp32 O, optional bf16 Ob, optional bf16 (O+Padd).
// 4 rows/block.
__global__ __launch_bounds__(256)
void ln_res_kernel(const float* __restrict__ X, const float* __restrict__ R,
                   const float* __restrict__ g, const float* __restrict__ bta,
                   float* __restrict__ O, unsigned short* __restrict__ Ob,
                   const float* __restrict__ Padd, unsigned short* __restrict__ Oadd,
                   int nrows)
{
    const int row = blockIdx.x * 4 + (threadIdx.x >> 6);
    if (row >= nrows) return;
    const int t = threadIdx.x & 63;
    const float* x = X + (size_t)row * 256;
    const float* r = R + (size_t)row * 256;
    float v[4];
    float s = 0.f;
    #pragma unroll
    for (int i = 0; i < 4; ++i) { int c = t + 64 * i; v[i] = x[c] + r[c]; s += v[i]; }
    #pragma unroll
    for (int off = 32; off >= 1; off >>= 1) s += __shfl_xor(s, off, 64);
    float mu = s * (1.f / 256.f);
    float s2 = 0.f;
    #pragma unroll
    for (int i = 0; i < 4; ++i) { float d = v[i] - mu; s2 += d * d; }
    #pragma unroll
    for (int off = 32; off >= 1; off >>= 1) s2 += __shfl_xor(s2, off, 64);
    float rstd = rsqrtf(s2 * (1.f / 256.f) + 1e-5f);
    #pragma unroll
    for (int i = 0; i < 4; ++i) {
        int c = t + 64 * i;
        float o = (v[i] - mu) * rstd * g[c] + bta[c];
        O[(size_t)row * 256 + c] = o;
        if (Ob) Ob[(size_t)row * 256 + c] = f2bf(o);
        if (Oadd) Oadd[(size_t)row * 256 + c] = f2bf(o + Padd[(size_t)row * 256 + c]);
    }
}

// ---------------------------------------------------------------------------
// 3D multi-scale deformable attention sampling; bf16 VALUE input, bf16 output.
__global__ __launch_bounds__(256)
void deform_kernel(const float* __restrict__ off, const float* __restrict__ awl,
                   const unsigned short* __restrict__ value, unsigned short* __restrict__ out)
{
    const int bq = blockIdx.x;
    const int b = bq / S_TOT;
    const int s = bq - b * S_TOT;
    const int t = threadIdx.x;

    __shared__ float aw_sh[128];
    __shared__ float aw_m[8], aw_s[8];
    __shared__ float2 tbl[128][8];
    __shared__ float4 racc[256];

    if (t < 128) aw_sh[t] = awl[(size_t)bq * 128 + t];
    __syncthreads();
    if (t < 8) {
        float m = -1e30f;
        #pragma unroll
        for (int i = 0; i < 16; ++i) m = fmaxf(m, aw_sh[t * 16 + i]);
        float su = 0.f;
        #pragma unroll
        for (int i = 0; i < 16; ++i) su += __expf(aw_sh[t * 16 + i] - m);
        aw_m[t] = m; aw_s[t] = su;
    }
    __syncthreads();

    if (t < 128) {
        const int h = t >> 4, lp = t & 15, l = lp >> 2;
        float aw = __expf(aw_sh[t] - aw_m[h]) / aw_s[h];
        int nq_, sq0;
        if (s < 13824)      { nq_ = 24; sq0 = 0; }
        else if (s < 15552) { nq_ = 12; sq0 = 13824; }
        else if (s < 15768) { nq_ = 6;  sq0 = 15552; }
        else                { nq_ = 3;  sq0 = 15768; }
        int tl = s - sq0;
        int iz = tl / (nq_ * nq_);
        int r1 = tl - iz * nq_ * nq_;
        int iy = r1 / nq_;
        int ix = r1 - iy * nq_;
        float invn = 1.f / (float)nq_;
        float rx = (ix + 0.5f) * invn;
        float ry = (iy + 0.5f) * invn;
        float rz = (iz + 0.5f) * invn;

        const int lvl_n[4]  = {24, 12, 6, 3};
        const int lvl_s0[4] = {0, 13824, 15552, 15768};
        const int nl = lvl_n[l];
        const int s0l = lvl_s0[l];
        const float* op = off + (size_t)bq * 384 + t * 3;
        float x = rx * nl + op[0] - 0.5f;
        float y = ry * nl + op[1] - 0.5f;
        float z = rz * nl + op[2] - 0.5f;
        float fx = floorf(x), fy = floorf(y), fz = floorf(z);
        int x0 = (int)fx, y0 = (int)fy, z0 = (int)fz;
        float wx1 = x - fx, wx0 = 1.f - wx1;
        float wy1 = y - fy, wy0 = 1.f - wy1;
        float wz1 = z - fz, wz0 = 1.f - wz1;
        int xc0 = min(max(x0, 0), nl - 1), xc1 = min(max(x0 + 1, 0), nl - 1);
        int yc0 = min(max(y0, 0), nl - 1), yc1 = min(max(y0 + 1, 0), nl - 1);
        int zc0 = min(max(z0, 0), nl - 1), zc1 = min(max(z0 + 1, 0), nl - 1);
        bool ox0 = (x0 >= 0) && (x0 < nl);
        bool ox1 = (x0 + 1 >= 0) && (x0 + 1 < nl);
        bool oy0 = (y0 >= 0) && (y0 < nl), oy1 = (y0 + 1 >= 0) && (y0 + 1 < nl);
        bool oz0 = (z0 >= 0) && (z0 < nl), oz1 = (z0 + 1 >= 0) && (z0 + 1 < nl);
        int base = b * S_TOT + s0l;
        #pragma unroll
        for (int c = 0; c < 8; ++c) {
            int dx = c & 1, dy = (c >> 1) & 1, dz = c >> 2;
            float w = (dx ? wx1 : wx0) * (dy ? wy1 : wy0) * (dz ? wz1 : wz0);
            bool ok = (dx ? ox1 : ox0) && (dy ? oy1 : oy0) && (dz ? oz1 : oz0);
            int xi = dx ? xc1 : xc0;
            int yi = dy ? yc1 : yc0;
            int zi = dz ? zc1 : zc0;
            int elem = ((base + (zi * nl + yi) * nl + xi) * 8 + h) * 32;
            tbl[t][c] = make_float2(ok ? w * aw : 0.f, __int_as_float(elem));
        }
    }
    __syncthreads();

    const int c4 = t & 7, lpg = (t >> 3) & 3, h2 = t >> 5;
    float4 acc = make_float4(0.f, 0.f, 0.f, 0.f);
    #pragma unroll
    for (int j = 0; j < 4; ++j) {
        const float2* row = tbl[h2 * 16 + lpg * 4 + j];
        #pragma unroll
        for (int c = 0; c < 8; ++c) {
            float2 e = row[c];
            ushort4 uv = *(const ushort4*)(value + (size_t)__float_as_int(e.y) + c4 * 4);
            acc.x += e.x * bf2f(uv.x); acc.y += e.x * bf2f(uv.y);
            acc.z += e.x * bf2f(uv.z); acc.w += e.x * bf2f(uv.w);
        }
    }
    racc[t] = acc;
    __syncthreads();
    if (lpg == 0) {
        float4 a = racc[t];
        #pragma unroll
        for (int gg = 1; gg < 4; ++gg) {
            float4 o = racc[t + gg * 8];
            a.x += o.x; a.y += o.y; a.z += o.z; a.w += o.w;
        }
        ushort4 r;
        r.x = f2bf(a.x); r.y = f2bf(a.y); r.z = f2bf(a.z); r.w = f2bf(a.w);
        *(ushort4*)(out + (size_t)bq * 256 + h2 * 32 + c4 * 4) = r;
    }
}

// ---------------------------------------------------------------------------
// small multi-head attention (decoder self-attn, Lk=80), online softmax.
__global__ __launch_bounds__(256)
void attn_kernel(const float* __restrict__ Q, const float* __restrict__ K,
                 const float* __restrict__ V, float* __restrict__ O,
                 int Lq, int Lk, float scale)
{
    const int nqc = (Lq + 3) >> 2;
    const int blk = blockIdx.x;
    const int qc = blk % nqc;
    const int bh = blk / nqc;
    const int h = bh & 7;
    const int b = bh >> 3;
    const int qi0 = qc * 4;
    const int t = threadIdx.x;
    const int c = t & 31, g = t >> 5;

    float qv[4];
    #pragma unroll
    for (int j = 0; j < 4; ++j)
        qv[j] = Q[((size_t)(b * Lq + qi0 + j)) * 256 + h * 32 + c];

    float m[4], l[4], acc[4];
    #pragma unroll
    for (int j = 0; j < 4; ++j) { m[j] = -1e30f; l[j] = 0.f; acc[j] = 0.f; }

    for (int k = g; k < Lk; k += 8) {
        const size_t roff = ((size_t)(b * Lk + k)) * 256 + h * 32 + c;
        float kv = K[roff];
        float vv = V[roff];
        #pragma unroll
        for (int j = 0; j < 4; ++j) {
            float p = qv[j] * kv;
            p += __shfl_xor(p, 16, 32);
            p += __shfl_xor(p, 8, 32);
            p += __shfl_xor(p, 4, 32);
            p += __shfl_xor(p, 2, 32);
            p += __shfl_xor(p, 1, 32);
            float sc = p * scale;
            float mn = fmaxf(m[j], sc);
            float fo = __expf(m[j] - mn);
            float w = __expf(sc - mn);
            l[j] = l[j] * fo + w;
            acc[j] = acc[j] * fo + w * vv;
            m[j] = mn;
        }
    }
    __shared__ float sm[8][4], sl[8][4], sacc[8][4][32];
    if (c == 0) {
        #pragma unroll
        for (int j = 0; j < 4; ++j) { sm[g][j] = m[j]; sl[g][j] = l[j]; }
    }
    #pragma unroll
    for (int j = 0; j < 4; ++j) sacc[g][j][c] = acc[j];
    __syncthreads();
    if (g == 0) {
        #pragma unroll
        for (int j = 0; j < 4; ++j) {
            float M = -1e30f;
            #pragma unroll
            for (int i = 0; i < 8; ++i) M = fmaxf(M, sm[i][j]);
            float L = 0.f, o = 0.f;
            #pragma unroll
            for (int i = 0; i < 8; ++i) {
                float e = __expf(sm[i][j] - M);
                L += sl[i][j] * e;
                o += sacc[i][j][c] * e;
            }
            O[((size_t)(b * Lq + qi0 + j)) * 256 + h * 32 + c] = o / L;
        }
    }
}

// ---------------------------------------------------------------------------
// split-K flash cross-attention, phase 1 — conflict-free b64 LDS layout.
// Ks/Vt/Ps use stride 34 (bank = 2*row + col: 2-way aliasing = free).
__global__ __launch_bounds__(256)
void xattn_part_kernel(const float* __restrict__ Q, const float* __restrict__ K,
                       const float* __restrict__ V,
                       const unsigned char* __restrict__ mask,
                       float* __restrict__ pm, float* __restrict__ pl,
                       float* __restrict__ po, int Lk, float scale)
{
    const int split = blockIdx.x;
    const int bh = blockIdx.y;
    const int b = bh >> 3, h = bh & 7;
    const int t = threadIdx.x;
    const int kk = t & 31;
    const int qg = t >> 5;

    __shared__ float Qs[80 * 32];      // [q][c]
    __shared__ float Ks[32][34];       // [key][c]
    __shared__ float Vt[32][34];       // [c][key]  (transposed V)
    __shared__ float Ps[80][34];       // [q][key]

    {   // stage Q tile with float4 loads
        const float* qb = Q + (size_t)(b * NQ) * 256 + h * 32;
        for (int i = t; i < 640; i += 256) {
            int q = i >> 3, cf = (i & 7) * 4;
            *(float4*)&Qs[q * 32 + cf] = *(const float4*)(qb + (size_t)q * 256 + cf);
        }
    }

    float m[10], l[10], acc[10];
    #pragma unroll
    for (int i = 0; i < 10; ++i) { m[i] = -1e9f; l[i] = 0.f; acc[i] = 0.f; }

    const int k_base = split * XCHUNK;
    for (int k0 = k_base; k0 < k_base + XCHUNK; k0 += 32) {
        __syncthreads();
        {   // stage K (row-major) + V (transposed): thread t -> key=t>>3, c4=(t&7)*4
            int key = t >> 3, c4 = (t & 7) * 4;
            int kg = k0 + key;
            float4 kv = make_float4(0.f, 0.f, 0.f, 0.f);
            float4 vv = make_float4(0.f, 0.f, 0.f, 0.f);
            if (kg < Lk) {
                size_t go = ((size_t)(b * Lk + kg)) * 256 + h * 32 + c4;
                kv = *(const float4*)(K + go);
                vv = *(const float4*)(V + go);
            }
            *(float2*)&Ks[key][c4]     = make_float2(kv.x, kv.y);
            *(float2*)&Ks[key][c4 + 2] = make_float2(kv.z, kv.w);
            Vt[c4 + 0][key] = vv.x;
            Vt[c4 + 1][key] = vv.y;
            Vt[c4 + 2][key] = vv.z;
            Vt[c4 + 3][key] = vv.w;
        }
        __syncthreads();

        // scores: thread (qg, kk) -> 10 queries x key kk, float2 over channels
        float s[10];
        #pragma unroll
        for (int i = 0; i < 10; ++i) s[i] = 0.f;
        #pragma unroll
        for (int c2 = 0; c2 < 16; ++c2) {
            float2 kv2 = *(const float2*)&Ks[kk][c2 * 2];
            #pragma unroll
            for (int i = 0; i < 10; ++i) {
                float2 q2 = *(const float2*)&Qs[(qg * 10 + i) * 32 + c2 * 2];
                s[i] += q2.x * kv2.x + q2.y * kv2.y;
            }
        }
        const int kg = k0 + kk;
        const bool valid = kg < Lk;
        float alpha[10];
        #pragma unroll
        for (int i = 0; i < 10; ++i) {
            const int q = qg * 10 + i;
            float sc = -1e9f;
            if (valid) {
                sc = s[i] * scale;
                if (mask[(size_t)q * Lk + kg]) sc = -1e9f;
            }
            float rm = sc;
            rm = fmaxf(rm, __shfl_xor(rm, 16, 32));
            rm = fmaxf(rm, __shfl_xor(rm, 8, 32));
            rm = fmaxf(rm, __shfl_xor(rm, 4, 32));
            rm = fmaxf(rm, __shfl_xor(rm, 2, 32));
            rm = fmaxf(rm, __shfl_xor(rm, 1, 32));
            float mn = fmaxf(m[i], rm);
            alpha[i] = __expf(m[i] - mn);
            float p = valid ? __expf(sc - mn) : 0.f;
            float ps = p;
            ps += __shfl_xor(ps, 16, 32);
            ps += __shfl_xor(ps, 8, 32);
            ps += __shfl_xor(ps, 4, 32);
            ps += __shfl_xor(ps, 2, 32);
            ps += __shfl_xor(ps, 1, 32);
            l[i] = l[i] * alpha[i] + ps;
            m[i] = mn;
            Ps[q][kk] = p;
        }
        __syncthreads();

        // PV: thread (qg, c=kk): float2 over keys; Ps reads broadcast within qg
        #pragma unroll
        for (int i = 0; i < 10; ++i) acc[i] *= alpha[i];
        #pragma unroll
        for (int k2 = 0; k2 < 16; ++k2) {
            float2 v2 = *(const float2*)&Vt[kk][k2 * 2];
            #pragma unroll
            for (int i = 0; i < 10; ++i) {
                float2 p2 = *(const float2*)&Ps[qg * 10 + i][k2 * 2];
                acc[i] += p2.x * v2.x + p2.y * v2.y;
            }
        }
    }

    const size_t base = ((size_t)bh * XSPLIT + split) * NQ;
    #pragma unroll
    for (int i = 0; i < 10; ++i) {
        const int q = qg * 10 + i;
        if (kk == 0) { pm[base + q] = m[i]; pl[base + q] = l[i]; }
        po[(base + q) * 32 + kk] = acc[i];
    }
}

// phase 2: merge XSPLIT partials per (b,h,q) -> O[B,NQ,256]
__global__ __launch_bounds__(64)
void xattn_merge_kernel(const float* __restrict__ pm, const float* __restrict__ pl,
                        const float* __restrict__ po, float* __restrict__ O)
{
    const int idx = blockIdx.x;
    const int bh = idx / NQ, q = idx - bh * NQ;
    const int b = bh >> 3, h = bh & 7;
    const int tt = threadIdx.x;
    if (tt >= 32) return;
    const int c = tt;
    float M = -1e30f;
    for (int s = 0; s < XSPLIT; ++s)
        M = fmaxf(M, pm[((size_t)bh * XSPLIT + s) * NQ + q]);
    float L = 0.f, o = 0.f;
    for (int s = 0; s < XSPLIT; ++s) {
        size_t base = ((size_t)bh * XSPLIT + s) * NQ + q;
        float e = __expf(pm[base] - M);
        L += pl[base] * e;
        o += po[base * 32 + c] * e;
    }
    O[((size_t)(b * NQ + q)) * 256 + h * 32 + c] = o / L;
}

// ---------------------------------------------------------------------------
extern "C" void kernel_launch(void* const* d_in, const int* in_sizes, int n_in,
                              void* d_out, int out_size, void* d_ws, size_t ws_size,
                              hipStream_t stream)
{
    const float* src       = (const float*)d_in[0];
    const float* pos       = (const float*)d_in[1];
    const float* lvl_pos   = (const float*)d_in[2];
    const float* tgt       = (const float*)d_in[3];
    const float* query_pos = (const float*)d_in[4];
    const float* eow  = (const float*)d_in[6];
    const float* eob  = (const float*)d_in[7];
    const float* eaw  = (const float*)d_in[8];
    const float* eab  = (const float*)d_in[9];
    const float* evw  = (const float*)d_in[10];
    const float* evb  = (const float*)d_in[11];
    const float* eouw = (const float*)d_in[12];
    const float* eoub = (const float*)d_in[13];
    const float* el1g = (const float*)d_in[14];
    const float* el1b = (const float*)d_in[15];
    const float* ef1w = (const float*)d_in[16];
    const float* ef1b = (const float*)d_in[17];
    const float* ef2w = (const float*)d_in[18];
    const float* ef2b = (const float*)d_in[19];
    const float* el2g = (const float*)d_in[20];
    const float* el2b = (const float*)d_in[21];
    const float* dsiw = (const float*)d_in[22];
    const float* dsib = (const float*)d_in[23];
    const float* dsow = (const float*)d_in[24];
    const float* dsob = (const float*)d_in[25];
    const float* dciw = (const float*)d_in[26];
    const float* dcib = (const float*)d_in[27];
    const float* dcow = (const float*)d_in[28];
    const float* dcob = (const float*)d_in[29];
    const float* dl1g = (const float*)d_in[30];
    const float* dl1b = (const float*)d_in[31];
    const float* dl2g = (const float*)d_in[32];
    const float* dl2b = (const float*)d_in[33];
    const float* dl3g = (const float*)d_in[34];
    const float* dl3b = (const float*)d_in[35];
    const float* df1w = (const float*)d_in[36];
    const float* df1b = (const float*)d_in[37];
    const float* df2w = (const float*)d_in[38];
    const float* df2b = (const float*)d_in[39];
    const unsigned char* amask = (const unsigned char*)d_in[40];

    const int MBS = B_SZ * S_TOT;                  // 31590
    const size_t nBSC = (size_t)MBS * 256;
    const size_t nP   = (size_t)MP * 256;

    float* ws = (float*)d_ws;
    float* f_out = ws; ws += nP;                   // encoder state / memory (fp32)
    float* f_mlp = ws; ws += nP;                   // proj output for residual
    float* f_off = ws; ws += (size_t)MBS * 384;    // enc offsets ; dec cross-K
    float* f_awl = ws; ws += (size_t)MBS * 128;    // enc aw logits
    float* f_val = ws; ws += nP;                   // enc fc2-out ; dec cross-V
    float* d_q   = ws; ws += 40960;
    float* d_qk  = ws; ws += 40960;
    float* d_sq  = ws; ws += 40960;
    float* d_sk  = ws; ws += 40960;
    float* d_sv  = ws; ws += 40960;
    float* d_ao  = ws; ws += 40960;
    float* d_pr  = ws; ws += 40960;
    float* d_h   = ws; ws += 163840;
    float* x_pm  = ws; ws += (size_t)16 * XSPLIT * NQ;
    float* x_pl  = ws; ws += (size_t)16 * XSPLIT * NQ;
    float* x_po  = ws; ws += (size_t)16 * XSPLIT * NQ * 32;

    unsigned short* bws = (unsigned short*)ws;
    unsigned short* b_mlp  = bws; bws += nP;            // bf16(state+pos)/dec memory+lvl_pos
    unsigned short* b_out  = bws; bws += nP;            // bf16 encoder state
    unsigned short* b_val  = bws; bws += nP;            // bf16 encoder value (deform input)
    unsigned short* b_hs   = bws; bws += (size_t)8192 * 1024;  // fc1-out / deform-out
    unsigned short* w_eow  = bws; bws += (size_t)6 * 384 * 256;
    unsigned short* w_eaw  = bws; bws += (size_t)6 * 128 * 256;
    unsigned short* w_evw  = bws; bws += (size_t)6 * 256 * 256;
    unsigned short* w_eouw = bws; bws += (size_t)6 * 256 * 256;
    unsigned short* w_ef1  = bws; bws += (size_t)6 * 1024 * 256;
    unsigned short* w_ef2  = bws; bws += (size_t)6 * 256 * 1024;
    unsigned short* w_dciw = bws; bws += (size_t)6 * 768 * 256;
    unsigned short* b_samp = b_hs;

    auto gemmb = [&](const unsigned short* A, const unsigned short* W, const float* bb,
                     void* Y, int M, int N, int K, int mode) {
        dim3 grid(N / 128, (M + 127) / 128);
        gemm_bf16_kernel<<<grid, dim3(256), 0, stream>>>(A, W, bb, Y, M, N, K, mode);
    };
    auto gemms = [&](const float* X, const float* W, const float* bb, float* Y,
                     int M, int N, int K, int relu) {
        dim3 grid(N / 64, (M + 63) / 64);
        gemm_bias_kernel<<<grid, dim3(256), 0, stream>>>(X, W, bb, Y, M, N, K, relu);
    };
    auto cast = [&](const float* x, unsigned short* o, size_t n) {
        int n4c = (int)(n / 4);
        cast_bf16_kernel<<<(n4c + 255) / 256, 256, 0, stream>>>(x, o, n4c);
    };

    const int n4 = (int)(nBSC / 4);
    const int dn4 = 40960 / 4;
    const float scale = 0.17677669529663687f;
    const int lnGrid = (MBS + 3) / 4;

    // weight conversions (once per launch)
    cast(eow,  w_eow,  (size_t)6 * 384 * 256);
    cast(eaw,  w_eaw,  (size_t)6 * 128 * 256);
    cast(evw,  w_evw,  (size_t)6 * 256 * 256);
    cast(eouw, w_eouw, (size_t)6 * 256 * 256);
    cast(ef1w, w_ef1,  (size_t)6 * 1024 * 256);
    cast(ef2w, w_ef2,  (size_t)6 * 256 * 1024);
    cast(dciw, w_dciw, (size_t)6 * 768 * 256);

    hipMemcpyAsync(f_out, src, nBSC * sizeof(float), hipMemcpyDeviceToDevice, stream);
    cast(src, b_out, nBSC);
    add_bf16_kernel<<<(n4 + 255) / 256, 256, 0, stream>>>(f_out, pos, b_mlp, n4);

    // ---------------- encoder ----------------
    for (int i = 0; i < 6; ++i) {
        gemmb(b_mlp, w_eow + (size_t)i * 384 * 256, eob + i * 384, f_off, MBS, 384, 256, 0);
        gemmb(b_mlp, w_eaw + (size_t)i * 128 * 256, eab + i * 128, f_awl, MBS, 128, 256, 0);
        gemmb(b_out, w_evw + (size_t)i * 256 * 256, evb + i * 256, b_val, MBS, 256, 256, 2);
        deform_kernel<<<MBS, 256, 0, stream>>>(f_off, f_awl, b_val, b_samp);
        gemmb(b_samp, w_eouw + (size_t)i * 256 * 256, eoub + i * 256, f_mlp, MBS, 256, 256, 0);
        ln_res_kernel<<<lnGrid, 256, 0, stream>>>(f_out, f_mlp, el1g + i * 256, el1b + i * 256,
                                                  f_out, b_out, (const float*)nullptr,
                                                  (unsigned short*)nullptr, MBS);
        for (int m0 = 0; m0 < MBS; m0 += 8192) {
            int mc = MBS - m0 < 8192 ? MBS - m0 : 8192;
            gemmb(b_out + (size_t)m0 * 256, w_ef1 + (size_t)i * 1024 * 256, ef1b + i * 1024,
                  b_hs, mc, 1024, 256, 1);
            gemmb(b_hs, w_ef2 + (size_t)i * 256 * 1024, ef2b + i * 256,
                  f_val + (size_t)m0 * 256, mc, 256, 1024, 0);
        }
        // ln2 also emits bf16(state + pos) for the next layer (lvl_pos after last layer)
        ln_res_kernel<<<lnGrid, 256, 0, stream>>>(f_out, f_val, el2g + i * 256, el2b + i * 256,
                                                  f_out, b_out, (i < 5 ? pos : lvl_pos),
                                                  b_mlp, MBS);
    }

    // ---------------- decoder ----------------
    hipMemcpyAsync(d_q, tgt, 40960 * sizeof(float), hipMemcpyDeviceToDevice, stream);

    for (int i = 0; i < 6; ++i) {
        const float* siw = dsiw + (size_t)i * 768 * 256;
        const float* sib = dsib + (size_t)i * 768;
        add_kernel<<<(dn4 + 255) / 256, 256, 0, stream>>>(d_q, query_pos, d_qk, dn4);
        gemms(d_qk, siw,             sib,       d_sq, 160, 256, 256, 0);
        gemms(d_qk, siw + 256 * 256, sib + 256, d_sk, 160, 256, 256, 0);
        gemms(d_q,  siw + 512 * 256, sib + 512, d_sv, 160, 256, 256, 0);
        attn_kernel<<<B_SZ * 8 * (NQ / 4), 256, 0, stream>>>(
            d_sq, d_sk, d_sv, d_ao, NQ, NQ, scale);
        gemms(d_ao, dsow + (size_t)i * 256 * 256, dsob + i * 256, d_pr, 160, 256, 256, 0);
        ln_res_kernel<<<40, 256, 0, stream>>>(d_q, d_pr, dl2g + i * 256, dl2b + i * 256,
                                              d_q, (unsigned short*)nullptr,
                                              (const float*)nullptr, (unsigned short*)nullptr, 160);

        const float* cib = dcib + (size_t)i * 768;
        add_kernel<<<(dn4 + 255) / 256, 256, 0, stream>>>(d_q, query_pos, d_qk, dn4);
        gemms(d_qk, dciw + (size_t)i * 768 * 256, cib, d_sq, 160, 256, 256, 0);
        gemmb(b_mlp, w_dciw + (size_t)i * 768 * 256 + 256 * 256, cib + 256,
              f_off, MBS, 256, 256, 0);                                        // cross-K
        gemmb(b_out, w_dciw + (size_t)i * 768 * 256 + 512 * 256, cib + 512,
              f_val, MBS, 256, 256, 0);                                        // cross-V
        xattn_part_kernel<<<dim3(XSPLIT, 16), 256, 0, stream>>>(
            d_sq, f_off, f_val, amask, x_pm, x_pl, x_po, S_TOT, scale);
        xattn_merge_kernel<<<16 * NQ, 64, 0, stream>>>(x_pm, x_pl, x_po, d_ao);
        gemms(d_ao, dcow + (size_t)i * 256 * 256, dcob + i * 256, d_pr, 160, 256, 256, 0);
        ln_res_kernel<<<40, 256, 0, stream>>>(d_q, d_pr, dl1g + i * 256, dl1b + i * 256,
                                              d_q, (unsigned short*)nullptr,
                                              (const float*)nullptr, (unsigned short*)nullptr, 160);

        gemms(d_q, df1w + (size_t)i * 1024 * 256, df1b + i * 1024, d_h, 160, 1024, 256, 1);
        gemms(d_h, df2w + (size_t)i * 256 * 1024, df2b + i * 256, d_pr, 160, 256, 1024, 0);
        ln_res_kernel<<<40, 256, 0, stream>>>(d_q, d_pr, dl3g + i * 256, dl3b + i * 256,
                                              d_q, (unsigned short*)nullptr,
                                              (const float*)nullptr, (unsigned short*)nullptr, 160);
    }

    hipMemcpyAsync(d_out, d_q, 40960 * sizeof(float), hipMemcpyDeviceToDevice, stream);
}

// Round 8
// 5627.938 us; speedup vs baseline: 1.0948x; 1.0948x over previous
//
#include <hip/hip_runtime.h>
#include <cstdint>

#define S_TOT 15795
#define B_SZ 2
#define NQ 80
#define XSPLIT 64
#define XCHUNK 256
#define MP 31616          // 31590 padded to multiple of 128

typedef __attribute__((ext_vector_type(8))) short short8;
typedef __attribute__((ext_vector_type(4))) float f32x4;

__device__ __forceinline__ unsigned short f2bf(float f) {
    unsigned u = __float_as_uint(f);
    unsigned r = u + 0x7fffu + ((u >> 16) & 1u);
    return (unsigned short)(r >> 16);
}
__device__ __forceinline__ float bf2f(unsigned short u) {
    return __uint_as_float((unsigned)u << 16);
}

// ---------------------------------------------------------------------------
__global__ __launch_bounds__(256)
void cast_bf16_kernel(const float* __restrict__ x, unsigned short* __restrict__ o, int n4)
{
    int i = blockIdx.x * 256 + threadIdx.x;
    if (i < n4) {
        float4 v = ((const float4*)x)[i];
        ushort4 r;
        r.x = f2bf(v.x); r.y = f2bf(v.y); r.z = f2bf(v.z); r.w = f2bf(v.w);
        ((ushort4*)o)[i] = r;
    }
}

// elementwise add, fp32 out
__global__ __launch_bounds__(256)
void add_kernel(const float* __restrict__ a, const float* __restrict__ b,
                float* __restrict__ o, int n4)
{
    int i = blockIdx.x * 256 + threadIdx.x;
    if (i < n4) {
        float4 av = ((const float4*)a)[i];
        float4 bv = ((const float4*)b)[i];
        float4 ov;
        ov.x = av.x + bv.x; ov.y = av.y + bv.y;
        ov.z = av.z + bv.z; ov.w = av.w + bv.w;
        ((float4*)o)[i] = ov;
    }
}

// elementwise add, bf16 out
__global__ __launch_bounds__(256)
void add_bf16_kernel(const float* __restrict__ a, const float* __restrict__ b,
                     unsigned short* __restrict__ o, int n4)
{
    int i = blockIdx.x * 256 + threadIdx.x;
    if (i < n4) {
        float4 av = ((const float4*)a)[i];
        float4 bv = ((const float4*)b)[i];
        ushort4 r;
        r.x = f2bf(av.x + bv.x); r.y = f2bf(av.y + bv.y);
        r.z = f2bf(av.z + bv.z); r.w = f2bf(av.w + bv.w);
        ((ushort4*)o)[i] = r;
    }
}

// ---------------------------------------------------------------------------
// pure-bf16 MFMA GEMM, register-staged DOUBLE-BUFFERED LDS (1 barrier/K-step).
// Y[M,N] = A[M,K](bf16) @ B[N,K](bf16)^T + bias.
// mode 0: fp32 out; 1: relu + bf16 out; 2: bf16 out (no relu).
// A readable to round-up-128(M) rows; N%128==0, K%32==0.
__global__ __launch_bounds__(256)
void gemm_bf16_kernel(const unsigned short* __restrict__ A,
                      const unsigned short* __restrict__ B,
                      const float* __restrict__ bias, void* __restrict__ Yv,
                      int M, int N, int K, int mode)
{
    __shared__ unsigned short As[2][128 * 32];
    __shared__ unsigned short Bs[2][128 * 32];
    const int t = threadIdx.x;
    const int wave = t >> 6, lane = t & 63;
    const int quad = lane >> 4, l16 = lane & 15;
    const int bm0 = blockIdx.y * 128;
    const int bn0 = blockIdx.x * 128;
    const int wm = (wave & 1) * 64;
    const int wn = (wave >> 1) * 64;
    const int srow = t >> 2;          // 0..63
    const int scol = (t & 3) * 8;     // 0,8,16,24

    f32x4 acc[4][4] = {};

    const unsigned short* pa0 = A + (size_t)(bm0 + srow) * K + scol;
    const unsigned short* pa1 = pa0 + (size_t)64 * K;
    const unsigned short* pb0 = B + (size_t)(bn0 + srow) * K + scol;
    const unsigned short* pb1 = pb0 + (size_t)64 * K;

    const int nk = K / 32;
    short8 a0 = *(const short8*)(pa0);
    short8 a1 = *(const short8*)(pa1);
    short8 b0 = *(const short8*)(pb0);
    short8 b1 = *(const short8*)(pb1);
    *(short8*)&As[0][srow * 32 + scol] = a0;
    *(short8*)&As[0][(srow + 64) * 32 + scol] = a1;
    *(short8*)&Bs[0][srow * 32 + scol] = b0;
    *(short8*)&Bs[0][(srow + 64) * 32 + scol] = b1;
    __syncthreads();

    for (int kb = 0; kb < nk; ++kb) {
        const int cur = kb & 1, nxt = cur ^ 1;
        const bool more = (kb + 1) < nk;
        if (more) {
            const int k0 = (kb + 1) * 32;
            a0 = *(const short8*)(pa0 + k0);
            a1 = *(const short8*)(pa1 + k0);
            b0 = *(const short8*)(pb0 + k0);
            b1 = *(const short8*)(pb1 + k0);
        }

        short8 af[4], bf[4];
        #pragma unroll
        for (int im = 0; im < 4; ++im)
            af[im] = *(const short8*)&As[cur][(wm + im * 16 + l16) * 32 + quad * 8];
        #pragma unroll
        for (int in = 0; in < 4; ++in)
            bf[in] = *(const short8*)&Bs[cur][(wn + in * 16 + l16) * 32 + quad * 8];
        #pragma unroll
        for (int im = 0; im < 4; ++im)
            #pragma unroll
            for (int in = 0; in < 4; ++in)
                acc[im][in] = __builtin_amdgcn_mfma_f32_16x16x32_bf16(
                    af[im], bf[in], acc[im][in], 0, 0, 0);

        if (more) {
            *(short8*)&As[nxt][srow * 32 + scol] = a0;
            *(short8*)&As[nxt][(srow + 64) * 32 + scol] = a1;
            *(short8*)&Bs[nxt][srow * 32 + scol] = b0;
            *(short8*)&Bs[nxt][(srow + 64) * 32 + scol] = b1;
        }
        __syncthreads();
    }

    // C/D: row = quad*4 + reg, col = l16
    #pragma unroll
    for (int im = 0; im < 4; ++im) {
        const int gm0 = bm0 + wm + im * 16 + quad * 4;
        #pragma unroll
        for (int in = 0; in < 4; ++in) {
            const int gn = bn0 + wn + in * 16 + l16;
            const float bv = bias[gn];
            #pragma unroll
            for (int r = 0; r < 4; ++r) {
                int row = gm0 + r;
                if (row < M) {
                    float o = acc[im][in][r] + bv;
                    if (mode == 0) {
                        ((float*)Yv)[(size_t)row * N + gn] = o;
                    } else {
                        if (mode == 1) o = fmaxf(o, 0.f);
                        ((unsigned short*)Yv)[(size_t)row * N + gn] = f2bf(o);
                    }
                }
            }
        }
    }
}

// ---------------------------------------------------------------------------
// fp32 GEMM for small decoder matrices. K%16==0, N%64==0.
__global__ __launch_bounds__(256)
void gemm_bias_kernel(const float* __restrict__ X, const float* __restrict__ W,
                      const float* __restrict__ bias, float* __restrict__ Y,
                      int M, int N, int K, int relu)
{
    __shared__ float Xs[16][68];
    __shared__ float Ws[16][68];
    const int bm0 = blockIdx.y * 64;
    const int bn0 = blockIdx.x * 64;
    const int t = threadIdx.x;
    const int tx = t & 15, ty = t >> 4;
    const int lr = t >> 2;
    const int lk = (t & 3) << 2;
    float acc[4][4] = {};
    const int xr = bm0 + lr;
    const int wr = bn0 + lr;
    const float* xp = X + (size_t)xr * K + lk;
    const float* wp = W + (size_t)wr * K + lk;
    for (int k0 = 0; k0 < K; k0 += 16) {
        float4 xv = make_float4(0.f, 0.f, 0.f, 0.f);
        if (xr < M) xv = *(const float4*)(xp + k0);
        float4 wv = make_float4(0.f, 0.f, 0.f, 0.f);
        if (wr < N) wv = *(const float4*)(wp + k0);
        Xs[lk + 0][lr] = xv.x; Xs[lk + 1][lr] = xv.y;
        Xs[lk + 2][lr] = xv.z; Xs[lk + 3][lr] = xv.w;
        Ws[lk + 0][lr] = wv.x; Ws[lk + 1][lr] = wv.y;
        Ws[lk + 2][lr] = wv.z; Ws[lk + 3][lr] = wv.w;
        __syncthreads();
        #pragma unroll
        for (int k = 0; k < 16; ++k) {
            float a0 = Xs[k][ty * 4 + 0], a1 = Xs[k][ty * 4 + 1];
            float a2 = Xs[k][ty * 4 + 2], a3 = Xs[k][ty * 4 + 3];
            float b0 = Ws[k][tx * 4 + 0], b1 = Ws[k][tx * 4 + 1];
            float b2 = Ws[k][tx * 4 + 2], b3 = Ws[k][tx * 4 + 3];
            acc[0][0] += a0 * b0; acc[0][1] += a0 * b1; acc[0][2] += a0 * b2; acc[0][3] += a0 * b3;
            acc[1][0] += a1 * b0; acc[1][1] += a1 * b1; acc[1][2] += a1 * b2; acc[1][3] += a1 * b3;
            acc[2][0] += a2 * b0; acc[2][1] += a2 * b1; acc[2][2] += a2 * b2; acc[2][3] += a2 * b3;
            acc[3][0] += a3 * b0; acc[3][1] += a3 * b1; acc[3][2] += a3 * b2; acc[3][3] += a3 * b3;
        }
        __syncthreads();
    }
    const int c0 = bn0 + tx * 4;
    float4 bv = *(const float4*)(bias + c0);
    #pragma unroll
    for (int i = 0; i < 4; ++i) {
        int r = bm0 + ty * 4 + i;
        if (r >= M) continue;
        float4 o;
        o.x = acc[i][0] + bv.x; o.y = acc[i][1] + bv.y;
        o.z = acc[i][2] + bv.z; o.w = acc[i][3] + bv.w;
        if (relu) {
            o.x = fmaxf(o.x, 0.f); o.y = fmaxf(o.y, 0.f);
            o.z = fmaxf(o.z, 0.f); o.w = fmaxf(o.w, 0.f);
        }
        *(float4*)(Y + (size_t)r * N + c0) = o;
    }
}

// ---------------------------------------------------------------------------
// LayerNorm(X + R)*g + b -> fp32 O, optional bf16 Ob, optional bf16 (O+Padd).
// 4 rows/block.
__global__ __launch_bounds__(256)
void ln_res_kernel(const float* __restrict__ X, const float* __restrict__ R,
                   const float* __restrict__ g, const float* __restrict__ bta,
                   float* __restrict__ O, unsigned short* __restrict__ Ob,
                   const float* __restrict__ Padd, unsigned short* __restrict__ Oadd,
                   int nrows)
{
    const int row = blockIdx.x * 4 + (threadIdx.x >> 6);
    if (row >= nrows) return;
    const int t = threadIdx.x & 63;
    const float* x = X + (size_t)row * 256;
    const float* r = R + (size_t)row * 256;
    float v[4];
    float s = 0.f;
    #pragma unroll
    for (int i = 0; i < 4; ++i) { int c = t + 64 * i; v[i] = x[c] + r[c]; s += v[i]; }
    #pragma unroll
    for (int off = 32; off >= 1; off >>= 1) s += __shfl_xor(s, off, 64);
    float mu = s * (1.f / 256.f);
    float s2 = 0.f;
    #pragma unroll
    for (int i = 0; i < 4; ++i) { float d = v[i] - mu; s2 += d * d; }
    #pragma unroll
    for (int off = 32; off >= 1; off >>= 1) s2 += __shfl_xor(s2, off, 64);
    float rstd = rsqrtf(s2 * (1.f / 256.f) + 1e-5f);
    #pragma unroll
    for (int i = 0; i < 4; ++i) {
        int c = t + 64 * i;
        float o = (v[i] - mu) * rstd * g[c] + bta[c];
        O[(size_t)row * 256 + c] = o;
        if (Ob) Ob[(size_t)row * 256 + c] = f2bf(o);
        if (Oadd) Oadd[(size_t)row * 256 + c] = f2bf(o + Padd[(size_t)row * 256 + c]);
    }
}

// ---------------------------------------------------------------------------
// 3D multi-scale deformable attention sampling; bf16 VALUE input, bf16 output.
__global__ __launch_bounds__(256)
void deform_kernel(const float* __restrict__ off, const float* __restrict__ awl,
                   const unsigned short* __restrict__ value, unsigned short* __restrict__ out)
{
    const int bq = blockIdx.x;
    const int b = bq / S_TOT;
    const int s = bq - b * S_TOT;
    const int t = threadIdx.x;

    __shared__ float aw_sh[128];
    __shared__ float aw_m[8], aw_s[8];
    __shared__ float2 tbl[128][8];
    __shared__ float4 racc[256];

    if (t < 128) aw_sh[t] = awl[(size_t)bq * 128 + t];
    __syncthreads();
    if (t < 8) {
        float m = -1e30f;
        #pragma unroll
        for (int i = 0; i < 16; ++i) m = fmaxf(m, aw_sh[t * 16 + i]);
        float su = 0.f;
        #pragma unroll
        for (int i = 0; i < 16; ++i) su += __expf(aw_sh[t * 16 + i] - m);
        aw_m[t] = m; aw_s[t] = su;
    }
    __syncthreads();

    if (t < 128) {
        const int h = t >> 4, lp = t & 15, l = lp >> 2;
        float aw = __expf(aw_sh[t] - aw_m[h]) / aw_s[h];
        int nq_, sq0;
        if (s < 13824)      { nq_ = 24; sq0 = 0; }
        else if (s < 15552) { nq_ = 12; sq0 = 13824; }
        else if (s < 15768) { nq_ = 6;  sq0 = 15552; }
        else                { nq_ = 3;  sq0 = 15768; }
        int tl = s - sq0;
        int iz = tl / (nq_ * nq_);
        int r1 = tl - iz * nq_ * nq_;
        int iy = r1 / nq_;
        int ix = r1 - iy * nq_;
        float invn = 1.f / (float)nq_;
        float rx = (ix + 0.5f) * invn;
        float ry = (iy + 0.5f) * invn;
        float rz = (iz + 0.5f) * invn;

        const int lvl_n[4]  = {24, 12, 6, 3};
        const int lvl_s0[4] = {0, 13824, 15552, 15768};
        const int nl = lvl_n[l];
        const int s0l = lvl_s0[l];
        const float* op = off + (size_t)bq * 384 + t * 3;
        float x = rx * nl + op[0] - 0.5f;
        float y = ry * nl + op[1] - 0.5f;
        float z = rz * nl + op[2] - 0.5f;
        float fx = floorf(x), fy = floorf(y), fz = floorf(z);
        int x0 = (int)fx, y0 = (int)fy, z0 = (int)fz;
        float wx1 = x - fx, wx0 = 1.f - wx1;
        float wy1 = y - fy, wy0 = 1.f - wy1;
        float wz1 = z - fz, wz0 = 1.f - wz1;
        int xc0 = min(max(x0, 0), nl - 1), xc1 = min(max(x0 + 1, 0), nl - 1);
        int yc0 = min(max(y0, 0), nl - 1), yc1 = min(max(y0 + 1, 0), nl - 1);
        int zc0 = min(max(z0, 0), nl - 1), zc1 = min(max(z0 + 1, 0), nl - 1);
        bool ox0 = (x0 >= 0) && (x0 < nl);
        bool ox1 = (x0 + 1 >= 0) && (x0 + 1 < nl);
        bool oy0 = (y0 >= 0) && (y0 < nl), oy1 = (y0 + 1 >= 0) && (y0 + 1 < nl);
        bool oz0 = (z0 >= 0) && (z0 < nl), oz1 = (z0 + 1 >= 0) && (z0 + 1 < nl);
        int base = b * S_TOT + s0l;
        #pragma unroll
        for (int c = 0; c < 8; ++c) {
            int dx = c & 1, dy = (c >> 1) & 1, dz = c >> 2;
            float w = (dx ? wx1 : wx0) * (dy ? wy1 : wy0) * (dz ? wz1 : wz0);
            bool ok = (dx ? ox1 : ox0) && (dy ? oy1 : oy0) && (dz ? oz1 : oz0);
            int xi = dx ? xc1 : xc0;
            int yi = dy ? yc1 : yc0;
            int zi = dz ? zc1 : zc0;
            int elem = ((base + (zi * nl + yi) * nl + xi) * 8 + h) * 32;
            tbl[t][c] = make_float2(ok ? w * aw : 0.f, __int_as_float(elem));
        }
    }
    __syncthreads();

    const int c4 = t & 7, lpg = (t >> 3) & 3, h2 = t >> 5;
    float4 acc = make_float4(0.f, 0.f, 0.f, 0.f);
    #pragma unroll
    for (int j = 0; j < 4; ++j) {
        const float2* row = tbl[h2 * 16 + lpg * 4 + j];
        #pragma unroll
        for (int c = 0; c < 8; ++c) {
            float2 e = row[c];
            ushort4 uv = *(const ushort4*)(value + (size_t)__float_as_int(e.y) + c4 * 4);
            acc.x += e.x * bf2f(uv.x); acc.y += e.x * bf2f(uv.y);
            acc.z += e.x * bf2f(uv.z); acc.w += e.x * bf2f(uv.w);
        }
    }
    racc[t] = acc;
    __syncthreads();
    if (lpg == 0) {
        float4 a = racc[t];
        #pragma unroll
        for (int gg = 1; gg < 4; ++gg) {
            float4 o = racc[t + gg * 8];
            a.x += o.x; a.y += o.y; a.z += o.z; a.w += o.w;
        }
        ushort4 r;
        r.x = f2bf(a.x); r.y = f2bf(a.y); r.z = f2bf(a.z); r.w = f2bf(a.w);
        *(ushort4*)(out + (size_t)bq * 256 + h2 * 32 + c4 * 4) = r;
    }
}

// ---------------------------------------------------------------------------
// small multi-head attention (decoder self-attn, Lk=80), online softmax.
__global__ __launch_bounds__(256)
void attn_kernel(const float* __restrict__ Q, const float* __restrict__ K,
                 const float* __restrict__ V, float* __restrict__ O,
                 int Lq, int Lk, float scale)
{
    const int nqc = (Lq + 3) >> 2;
    const int blk = blockIdx.x;
    const int qc = blk % nqc;
    const int bh = blk / nqc;
    const int h = bh & 7;
    const int b = bh >> 3;
    const int qi0 = qc * 4;
    const int t = threadIdx.x;
    const int c = t & 31, g = t >> 5;

    float qv[4];
    #pragma unroll
    for (int j = 0; j < 4; ++j)
        qv[j] = Q[((size_t)(b * Lq + qi0 + j)) * 256 + h * 32 + c];

    float m[4], l[4], acc[4];
    #pragma unroll
    for (int j = 0; j < 4; ++j) { m[j] = -1e30f; l[j] = 0.f; acc[j] = 0.f; }

    for (int k = g; k < Lk; k += 8) {
        const size_t roff = ((size_t)(b * Lk + k)) * 256 + h * 32 + c;
        float kv = K[roff];
        float vv = V[roff];
        #pragma unroll
        for (int j = 0; j < 4; ++j) {
            float p = qv[j] * kv;
            p += __shfl_xor(p, 16, 32);
            p += __shfl_xor(p, 8, 32);
            p += __shfl_xor(p, 4, 32);
            p += __shfl_xor(p, 2, 32);
            p += __shfl_xor(p, 1, 32);
            float sc = p * scale;
            float mn = fmaxf(m[j], sc);
            float fo = __expf(m[j] - mn);
            float w = __expf(sc - mn);
            l[j] = l[j] * fo + w;
            acc[j] = acc[j] * fo + w * vv;
            m[j] = mn;
        }
    }
    __shared__ float sm[8][4], sl[8][4], sacc[8][4][32];
    if (c == 0) {
        #pragma unroll
        for (int j = 0; j < 4; ++j) { sm[g][j] = m[j]; sl[g][j] = l[j]; }
    }
    #pragma unroll
    for (int j = 0; j < 4; ++j) sacc[g][j][c] = acc[j];
    __syncthreads();
    if (g == 0) {
        #pragma unroll
        for (int j = 0; j < 4; ++j) {
            float M = -1e30f;
            #pragma unroll
            for (int i = 0; i < 8; ++i) M = fmaxf(M, sm[i][j]);
            float L = 0.f, o = 0.f;
            #pragma unroll
            for (int i = 0; i < 8; ++i) {
                float e = __expf(sm[i][j] - M);
                L += sl[i][j] * e;
                o += sacc[i][j][c] * e;
            }
            O[((size_t)(b * Lq + qi0 + j)) * 256 + h * 32 + c] = o / L;
        }
    }
}

// ---------------------------------------------------------------------------
// split-K flash cross-attention, phase 1 (round-4/6 proven version).
__global__ __launch_bounds__(256)
void xattn_part_kernel(const float* __restrict__ Q, const float* __restrict__ K,
                       const float* __restrict__ V,
                       const unsigned char* __restrict__ mask,
                       float* __restrict__ pm, float* __restrict__ pl,
                       float* __restrict__ po, int Lk, float scale)
{
    const int split = blockIdx.x;
    const int bh = blockIdx.y;
    const int b = bh >> 3, h = bh & 7;
    const int t = threadIdx.x;
    const int kk = t & 31;
    const int qg = t >> 5;

    __shared__ float Qs[80 * 32];
    __shared__ float Ks[32][33];
    __shared__ float Vs[32][33];
    __shared__ float Ps[80][33];

    for (int i = t; i < 2560; i += 256) {
        int q = i >> 5, c = i & 31;
        Qs[i] = Q[((size_t)(b * NQ + q)) * 256 + h * 32 + c];
    }

    float m[10], l[10], acc[10];
    #pragma unroll
    for (int i = 0; i < 10; ++i) { m[i] = -1e9f; l[i] = 0.f; acc[i] = 0.f; }

    const int k_base = split * XCHUNK;
    for (int k0 = k_base; k0 < k_base + XCHUNK; k0 += 32) {
        __syncthreads();
        {
            int key = t >> 3, c4 = (t & 7) * 4;
            int kg = k0 + key;
            float4 kv = make_float4(0.f, 0.f, 0.f, 0.f);
            float4 vv = make_float4(0.f, 0.f, 0.f, 0.f);
            if (kg < Lk) {
                size_t go = ((size_t)(b * Lk + kg)) * 256 + h * 32 + c4;
                kv = *(const float4*)(K + go);
                vv = *(const float4*)(V + go);
            }
            Ks[key][c4 + 0] = kv.x; Ks[key][c4 + 1] = kv.y;
            Ks[key][c4 + 2] = kv.z; Ks[key][c4 + 3] = kv.w;
            Vs[key][c4 + 0] = vv.x; Vs[key][c4 + 1] = vv.y;
            Vs[key][c4 + 2] = vv.z; Vs[key][c4 + 3] = vv.w;
        }
        __syncthreads();

        float s[10];
        #pragma unroll
        for (int i = 0; i < 10; ++i) s[i] = 0.f;
        #pragma unroll 8
        for (int c = 0; c < 32; ++c) {
            float kv = Ks[kk][c];
            #pragma unroll
            for (int i = 0; i < 10; ++i) s[i] += Qs[(qg * 10 + i) * 32 + c] * kv;
        }
        const int kg = k0 + kk;
        const bool valid = kg < Lk;
        float alpha[10];
        #pragma unroll
        for (int i = 0; i < 10; ++i) {
            const int q = qg * 10 + i;
            float sc = -1e9f;
            if (valid) {
                sc = s[i] * scale;
                if (mask[(size_t)q * Lk + kg]) sc = -1e9f;
            }
            float rm = sc;
            rm = fmaxf(rm, __shfl_xor(rm, 16, 32));
            rm = fmaxf(rm, __shfl_xor(rm, 8, 32));
            rm = fmaxf(rm, __shfl_xor(rm, 4, 32));
            rm = fmaxf(rm, __shfl_xor(rm, 2, 32));
            rm = fmaxf(rm, __shfl_xor(rm, 1, 32));
            float mn = fmaxf(m[i], rm);
            alpha[i] = __expf(m[i] - mn);
            float p = valid ? __expf(sc - mn) : 0.f;
            float ps = p;
            ps += __shfl_xor(ps, 16, 32);
            ps += __shfl_xor(ps, 8, 32);
            ps += __shfl_xor(ps, 4, 32);
            ps += __shfl_xor(ps, 2, 32);
            ps += __shfl_xor(ps, 1, 32);
            l[i] = l[i] * alpha[i] + ps;
            m[i] = mn;
            Ps[q][kk] = p;
        }
        __syncthreads();

        #pragma unroll
        for (int i = 0; i < 10; ++i) acc[i] *= alpha[i];
        #pragma unroll 8
        for (int kj = 0; kj < 32; ++kj) {
            float v = Vs[kj][kk];
            #pragma unroll
            for (int i = 0; i < 10; ++i) acc[i] += Ps[qg * 10 + i][kj] * v;
        }
    }

    const size_t base = ((size_t)bh * XSPLIT + split) * NQ;
    #pragma unroll
    for (int i = 0; i < 10; ++i) {
        const int q = qg * 10 + i;
        if (kk == 0) { pm[base + q] = m[i]; pl[base + q] = l[i]; }
        po[(base + q) * 32 + kk] = acc[i];
    }
}

// phase 2: merge XSPLIT partials per (b,h,q) -> O[B,NQ,256]
__global__ __launch_bounds__(64)
void xattn_merge_kernel(const float* __restrict__ pm, const float* __restrict__ pl,
                        const float* __restrict__ po, float* __restrict__ O)
{
    const int idx = blockIdx.x;
    const int bh = idx / NQ, q = idx - bh * NQ;
    const int b = bh >> 3, h = bh & 7;
    const int tt = threadIdx.x;
    if (tt >= 32) return;
    const int c = tt;
    float M = -1e30f;
    for (int s = 0; s < XSPLIT; ++s)
        M = fmaxf(M, pm[((size_t)bh * XSPLIT + s) * NQ + q]);
    float L = 0.f, o = 0.f;
    for (int s = 0; s < XSPLIT; ++s) {
        size_t base = ((size_t)bh * XSPLIT + s) * NQ + q;
        float e = __expf(pm[base] - M);
        L += pl[base] * e;
        o += po[base * 32 + c] * e;
    }
    O[((size_t)(b * NQ + q)) * 256 + h * 32 + c] = o / L;
}

// ---------------------------------------------------------------------------
extern "C" void kernel_launch(void* const* d_in, const int* in_sizes, int n_in,
                              void* d_out, int out_size, void* d_ws, size_t ws_size,
                              hipStream_t stream)
{
    const float* src       = (const float*)d_in[0];
    const float* pos       = (const float*)d_in[1];
    const float* lvl_pos   = (const float*)d_in[2];
    const float* tgt       = (const float*)d_in[3];
    const float* query_pos = (const float*)d_in[4];
    const float* eow  = (const float*)d_in[6];
    const float* eob  = (const float*)d_in[7];
    const float* eaw  = (const float*)d_in[8];
    const float* eab  = (const float*)d_in[9];
    const float* evw  = (const float*)d_in[10];
    const float* evb  = (const float*)d_in[11];
    const float* eouw = (const float*)d_in[12];
    const float* eoub = (const float*)d_in[13];
    const float* el1g = (const float*)d_in[14];
    const float* el1b = (const float*)d_in[15];
    const float* ef1w = (const float*)d_in[16];
    const float* ef1b = (const float*)d_in[17];
    const float* ef2w = (const float*)d_in[18];
    const float* ef2b = (const float*)d_in[19];
    const float* el2g = (const float*)d_in[20];
    const float* el2b = (const float*)d_in[21];
    const float* dsiw = (const float*)d_in[22];
    const float* dsib = (const float*)d_in[23];
    const float* dsow = (const float*)d_in[24];
    const float* dsob = (const float*)d_in[25];
    const float* dciw = (const float*)d_in[26];
    const float* dcib = (const float*)d_in[27];
    const float* dcow = (const float*)d_in[28];
    const float* dcob = (const float*)d_in[29];
    const float* dl1g = (const float*)d_in[30];
    const float* dl1b = (const float*)d_in[31];
    const float* dl2g = (const float*)d_in[32];
    const float* dl2b = (const float*)d_in[33];
    const float* dl3g = (const float*)d_in[34];
    const float* dl3b = (const float*)d_in[35];
    const float* df1w = (const float*)d_in[36];
    const float* df1b = (const float*)d_in[37];
    const float* df2w = (const float*)d_in[38];
    const float* df2b = (const float*)d_in[39];
    const unsigned char* amask = (const unsigned char*)d_in[40];

    const int MBS = B_SZ * S_TOT;                  // 31590
    const size_t nBSC = (size_t)MBS * 256;
    const size_t nP   = (size_t)MP * 256;

    float* ws = (float*)d_ws;
    float* f_out = ws; ws += nP;                   // encoder state / memory (fp32)
    float* f_mlp = ws; ws += nP;                   // proj output for residual
    float* f_off = ws; ws += (size_t)MBS * 384;    // enc offsets ; dec cross-K
    float* f_awl = ws; ws += (size_t)MBS * 128;    // enc aw logits
    float* f_val = ws; ws += nP;                   // enc fc2-out ; dec cross-V
    float* d_q   = ws; ws += 40960;
    float* d_qk  = ws; ws += 40960;
    float* d_sq  = ws; ws += 40960;
    float* d_sk  = ws; ws += 40960;
    float* d_sv  = ws; ws += 40960;
    float* d_ao  = ws; ws += 40960;
    float* d_pr  = ws; ws += 40960;
    float* d_h   = ws; ws += 163840;
    float* x_pm  = ws; ws += (size_t)16 * XSPLIT * NQ;
    float* x_pl  = ws; ws += (size_t)16 * XSPLIT * NQ;
    float* x_po  = ws; ws += (size_t)16 * XSPLIT * NQ * 32;

    unsigned short* bws = (unsigned short*)ws;
    unsigned short* b_mlp  = bws; bws += nP;            // bf16(state+pos)/dec memory+lvl_pos
    unsigned short* b_out  = bws; bws += nP;            // bf16 encoder state
    unsigned short* b_val  = bws; bws += nP;            // bf16 encoder value (deform input)
    unsigned short* b_hs   = bws; bws += (size_t)8192 * 1024;  // fc1-out / deform-out
    unsigned short* w_eow  = bws; bws += (size_t)6 * 384 * 256;
    unsigned short* w_eaw  = bws; bws += (size_t)6 * 128 * 256;
    unsigned short* w_evw  = bws; bws += (size_t)6 * 256 * 256;
    unsigned short* w_eouw = bws; bws += (size_t)6 * 256 * 256;
    unsigned short* w_ef1  = bws; bws += (size_t)6 * 1024 * 256;
    unsigned short* w_ef2  = bws; bws += (size_t)6 * 256 * 1024;
    unsigned short* w_dciw = bws; bws += (size_t)6 * 768 * 256;
    unsigned short* b_samp = b_hs;

    auto gemmb = [&](const unsigned short* A, const unsigned short* W, const float* bb,
                     void* Y, int M, int N, int K, int mode) {
        dim3 grid(N / 128, (M + 127) / 128);
        gemm_bf16_kernel<<<grid, dim3(256), 0, stream>>>(A, W, bb, Y, M, N, K, mode);
    };
    auto gemms = [&](const float* X, const float* W, const float* bb, float* Y,
                     int M, int N, int K, int relu) {
        dim3 grid(N / 64, (M + 63) / 64);
        gemm_bias_kernel<<<grid, dim3(256), 0, stream>>>(X, W, bb, Y, M, N, K, relu);
    };
    auto cast = [&](const float* x, unsigned short* o, size_t n) {
        int n4c = (int)(n / 4);
        cast_bf16_kernel<<<(n4c + 255) / 256, 256, 0, stream>>>(x, o, n4c);
    };

    const int n4 = (int)(nBSC / 4);
    const int dn4 = 40960 / 4;
    const float scale = 0.17677669529663687f;
    const int lnGrid = (MBS + 3) / 4;

    // weight conversions (once per launch)
    cast(eow,  w_eow,  (size_t)6 * 384 * 256);
    cast(eaw,  w_eaw,  (size_t)6 * 128 * 256);
    cast(evw,  w_evw,  (size_t)6 * 256 * 256);
    cast(eouw, w_eouw, (size_t)6 * 256 * 256);
    cast(ef1w, w_ef1,  (size_t)6 * 1024 * 256);
    cast(ef2w, w_ef2,  (size_t)6 * 256 * 1024);
    cast(dciw, w_dciw, (size_t)6 * 768 * 256);

    hipMemcpyAsync(f_out, src, nBSC * sizeof(float), hipMemcpyDeviceToDevice, stream);
    cast(src, b_out, nBSC);
    add_bf16_kernel<<<(n4 + 255) / 256, 256, 0, stream>>>(f_out, pos, b_mlp, n4);

    // ---------------- encoder ----------------
    for (int i = 0; i < 6; ++i) {
        gemmb(b_mlp, w_eow + (size_t)i * 384 * 256, eob + i * 384, f_off, MBS, 384, 256, 0);
        gemmb(b_mlp, w_eaw + (size_t)i * 128 * 256, eab + i * 128, f_awl, MBS, 128, 256, 0);
        gemmb(b_out, w_evw + (size_t)i * 256 * 256, evb + i * 256, b_val, MBS, 256, 256, 2);
        deform_kernel<<<MBS, 256, 0, stream>>>(f_off, f_awl, b_val, b_samp);
        gemmb(b_samp, w_eouw + (size_t)i * 256 * 256, eoub + i * 256, f_mlp, MBS, 256, 256, 0);
        ln_res_kernel<<<lnGrid, 256, 0, stream>>>(f_out, f_mlp, el1g + i * 256, el1b + i * 256,
                                                  f_out, b_out, (const float*)nullptr,
                                                  (unsigned short*)nullptr, MBS);
        for (int m0 = 0; m0 < MBS; m0 += 8192) {
            int mc = MBS - m0 < 8192 ? MBS - m0 : 8192;
            gemmb(b_out + (size_t)m0 * 256, w_ef1 + (size_t)i * 1024 * 256, ef1b + i * 1024,
                  b_hs, mc, 1024, 256, 1);
            gemmb(b_hs, w_ef2 + (size_t)i * 256 * 1024, ef2b + i * 256,
                  f_val + (size_t)m0 * 256, mc, 256, 1024, 0);
        }
        // ln2 also emits bf16(state + pos) for the next layer (lvl_pos after last layer)
        ln_res_kernel<<<lnGrid, 256, 0, stream>>>(f_out, f_val, el2g + i * 256, el2b + i * 256,
                                                  f_out, b_out, (i < 5 ? pos : lvl_pos),
                                                  b_mlp, MBS);
    }

    // ---------------- decoder ----------------
    hipMemcpyAsync(d_q, tgt, 40960 * sizeof(float), hipMemcpyDeviceToDevice, stream);

    for (int i = 0; i < 6; ++i) {
        const float* siw = dsiw + (size_t)i * 768 * 256;
        const float* sib = dsib + (size_t)i * 768;
        add_kernel<<<(dn4 + 255) / 256, 256, 0, stream>>>(d_q, query_pos, d_qk, dn4);
        gemms(d_qk, siw,             sib,       d_sq, 160, 256, 256, 0);
        gemms(d_qk, siw + 256 * 256, sib + 256, d_sk, 160, 256, 256, 0);
        gemms(d_q,  siw + 512 * 256, sib + 512, d_sv, 160, 256, 256, 0);
        attn_kernel<<<B_SZ * 8 * (NQ / 4), 256, 0, stream>>>(
            d_sq, d_sk, d_sv, d_ao, NQ, NQ, scale);
        gemms(d_ao, dsow + (size_t)i * 256 * 256, dsob + i * 256, d_pr, 160, 256, 256, 0);
        ln_res_kernel<<<40, 256, 0, stream>>>(d_q, d_pr, dl2g + i * 256, dl2b + i * 256,
                                              d_q, (unsigned short*)nullptr,
                                              (const float*)nullptr, (unsigned short*)nullptr, 160);

        const float* cib = dcib + (size_t)i * 768;
        add_kernel<<<(dn4 + 255) / 256, 256, 0, stream>>>(d_q, query_pos, d_qk, dn4);
        gemms(d_qk, dciw + (size_t)i * 768 * 256, cib, d_sq, 160, 256, 256, 0);
        gemmb(b_mlp, w_dciw + (size_t)i * 768 * 256 + 256 * 256, cib + 256,
              f_off, MBS, 256, 256, 0);                                        // cross-K
        gemmb(b_out, w_dciw + (size_t)i * 768 * 256 + 512 * 256, cib + 512,
              f_val, MBS, 256, 256, 0);                                        // cross-V
        xattn_part_kernel<<<dim3(XSPLIT, 16), 256, 0, stream>>>(
            d_sq, f_off, f_val, amask, x_pm, x_pl, x_po, S_TOT, scale);
        xattn_merge_kernel<<<16 * NQ, 64, 0, stream>>>(x_pm, x_pl, x_po, d_ao);
        gemms(d_ao, dcow + (size_t)i * 256 * 256, dcob + i * 256, d_pr, 160, 256, 256, 0);
        ln_res_kernel<<<40, 256, 0, stream>>>(d_q, d_pr, dl1g + i * 256, dl1b + i * 256,
                                              d_q, (unsigned short*)nullptr,
                                              (const float*)nullptr, (unsigned short*)nullptr, 160);

        gemms(d_q, df1w + (size_t)i * 1024 * 256, df1b + i * 1024, d_h, 160, 1024, 256, 1);
        gemms(d_h, df2w + (size_t)i * 256 * 1024, df2b + i * 256, d_pr, 160, 256, 1024, 0);
        ln_res_kernel<<<40, 256, 0, stream>>>(d_q, d_pr, dl3g + i * 256, dl3b + i * 256,
                                              d_q, (unsigned short*)nullptr,
                                              (const float*)nullptr, (unsigned short*)nullptr, 160);
    }

    hipMemcpyAsync(d_out, d_q, 40960 * sizeof(float), hipMemcpyDeviceToDevice, stream);
}

// Round 10
// 4997.545 us; speedup vs baseline: 1.2329x; 1.1261x over previous
//
#include <hip/hip_runtime.h>
#include <cstdint>

#define S_TOT 15795
#define B_SZ 2
#define NQ 80
#define XSPLIT 64
#define XCHUNK 256
#define MP 31616          // 31590 padded to multiple of 128

typedef __attribute__((ext_vector_type(8))) short short8;
typedef __attribute__((ext_vector_type(4))) float f32x4;

__device__ __forceinline__ unsigned short f2bf(float f) {
    unsigned u = __float_as_uint(f);
    unsigned r = u + 0x7fffu + ((u >> 16) & 1u);
    return (unsigned short)(r >> 16);
}

// ---------------------------------------------------------------------------
__global__ __launch_bounds__(256)
void cast_bf16_kernel(const float* __restrict__ x, unsigned short* __restrict__ o, int n4)
{
    int i = blockIdx.x * 256 + threadIdx.x;
    if (i < n4) {
        float4 v = ((const float4*)x)[i];
        ushort4 r;
        r.x = f2bf(v.x); r.y = f2bf(v.y); r.z = f2bf(v.z); r.w = f2bf(v.w);
        ((ushort4*)o)[i] = r;
    }
}

// elementwise add, fp32 out
__global__ __launch_bounds__(256)
void add_kernel(const float* __restrict__ a, const float* __restrict__ b,
                float* __restrict__ o, int n4)
{
    int i = blockIdx.x * 256 + threadIdx.x;
    if (i < n4) {
        float4 av = ((const float4*)a)[i];
        float4 bv = ((const float4*)b)[i];
        float4 ov;
        ov.x = av.x + bv.x; ov.y = av.y + bv.y;
        ov.z = av.z + bv.z; ov.w = av.w + bv.w;
        ((float4*)o)[i] = ov;
    }
}

// elementwise add, bf16 out
__global__ __launch_bounds__(256)
void add_bf16_kernel(const float* __restrict__ a, const float* __restrict__ b,
                     unsigned short* __restrict__ o, int n4)
{
    int i = blockIdx.x * 256 + threadIdx.x;
    if (i < n4) {
        float4 av = ((const float4*)a)[i];
        float4 bv = ((const float4*)b)[i];
        ushort4 r;
        r.x = f2bf(av.x + bv.x); r.y = f2bf(av.y + bv.y);
        r.z = f2bf(av.z + bv.z); r.w = f2bf(av.w + bv.w);
        ((ushort4*)o)[i] = r;
    }
}

// ---------------------------------------------------------------------------
// pure-bf16 MFMA GEMM, register-staged DOUBLE-BUFFERED LDS (1 barrier/K-step).
// Y[M,N] = A[M,K](bf16) @ B[N,K](bf16)^T + bias.
// mode 0: fp32 out; 1: relu + bf16 out; 2: bf16 out (no relu).
// A readable to round-up-128(M) rows; N%128==0, K%32==0.
__global__ __launch_bounds__(256)
void gemm_bf16_kernel(const unsigned short* __restrict__ A,
                      const unsigned short* __restrict__ B,
                      const float* __restrict__ bias, void* __restrict__ Yv,
                      int M, int N, int K, int mode)
{
    __shared__ unsigned short As[2][128 * 32];
    __shared__ unsigned short Bs[2][128 * 32];
    const int t = threadIdx.x;
    const int wave = t >> 6, lane = t & 63;
    const int quad = lane >> 4, l16 = lane & 15;
    const int bm0 = blockIdx.y * 128;
    const int bn0 = blockIdx.x * 128;
    const int wm = (wave & 1) * 64;
    const int wn = (wave >> 1) * 64;
    const int srow = t >> 2;          // 0..63
    const int scol = (t & 3) * 8;     // 0,8,16,24

    f32x4 acc[4][4] = {};

    const unsigned short* pa0 = A + (size_t)(bm0 + srow) * K + scol;
    const unsigned short* pa1 = pa0 + (size_t)64 * K;
    const unsigned short* pb0 = B + (size_t)(bn0 + srow) * K + scol;
    const unsigned short* pb1 = pb0 + (size_t)64 * K;

    const int nk = K / 32;
    short8 a0 = *(const short8*)(pa0);
    short8 a1 = *(const short8*)(pa1);
    short8 b0 = *(const short8*)(pb0);
    short8 b1 = *(const short8*)(pb1);
    *(short8*)&As[0][srow * 32 + scol] = a0;
    *(short8*)&As[0][(srow + 64) * 32 + scol] = a1;
    *(short8*)&Bs[0][srow * 32 + scol] = b0;
    *(short8*)&Bs[0][(srow + 64) * 32 + scol] = b1;
    __syncthreads();

    for (int kb = 0; kb < nk; ++kb) {
        const int cur = kb & 1, nxt = cur ^ 1;
        const bool more = (kb + 1) < nk;
        if (more) {
            const int k0 = (kb + 1) * 32;
            a0 = *(const short8*)(pa0 + k0);
            a1 = *(const short8*)(pa1 + k0);
            b0 = *(const short8*)(pb0 + k0);
            b1 = *(const short8*)(pb1 + k0);
        }

        short8 af[4], bf[4];
        #pragma unroll
        for (int im = 0; im < 4; ++im)
            af[im] = *(const short8*)&As[cur][(wm + im * 16 + l16) * 32 + quad * 8];
        #pragma unroll
        for (int in = 0; in < 4; ++in)
            bf[in] = *(const short8*)&Bs[cur][(wn + in * 16 + l16) * 32 + quad * 8];
        #pragma unroll
        for (int im = 0; im < 4; ++im)
            #pragma unroll
            for (int in = 0; in < 4; ++in)
                acc[im][in] = __builtin_amdgcn_mfma_f32_16x16x32_bf16(
                    af[im], bf[in], acc[im][in], 0, 0, 0);

        if (more) {
            *(short8*)&As[nxt][srow * 32 + scol] = a0;
            *(short8*)&As[nxt][(srow + 64) * 32 + scol] = a1;
            *(short8*)&Bs[nxt][srow * 32 + scol] = b0;
            *(short8*)&Bs[nxt][(srow + 64) * 32 + scol] = b1;
        }
        __syncthreads();
    }

    // C/D: row = quad*4 + reg, col = l16
    #pragma unroll
    for (int im = 0; im < 4; ++im) {
        const int gm0 = bm0 + wm + im * 16 + quad * 4;
        #pragma unroll
        for (int in = 0; in < 4; ++in) {
            const int gn = bn0 + wn + in * 16 + l16;
            const float bv = bias[gn];
            #pragma unroll
            for (int r = 0; r < 4; ++r) {
                int row = gm0 + r;
                if (row < M) {
                    float o = acc[im][in][r] + bv;
                    if (mode == 0) {
                        ((float*)Yv)[(size_t)row * N + gn] = o;
                    } else {
                        if (mode == 1) o = fmaxf(o, 0.f);
                        ((unsigned short*)Yv)[(size_t)row * N + gn] = f2bf(o);
                    }
                }
            }
        }
    }
}

// ---------------------------------------------------------------------------
// fp32 GEMM for small decoder matrices. K%16==0, N%64==0.
__global__ __launch_bounds__(256)
void gemm_bias_kernel(const float* __restrict__ X, const float* __restrict__ W,
                      const float* __restrict__ bias, float* __restrict__ Y,
                      int M, int N, int K, int relu)
{
    __shared__ float Xs[16][68];
    __shared__ float Ws[16][68];
    const int bm0 = blockIdx.y * 64;
    const int bn0 = blockIdx.x * 64;
    const int t = threadIdx.x;
    const int tx = t & 15, ty = t >> 4;
    const int lr = t >> 2;
    const int lk = (t & 3) << 2;
    float acc[4][4] = {};
    const int xr = bm0 + lr;
    const int wr = bn0 + lr;
    const float* xp = X + (size_t)xr * K + lk;
    const float* wp = W + (size_t)wr * K + lk;
    for (int k0 = 0; k0 < K; k0 += 16) {
        float4 xv = make_float4(0.f, 0.f, 0.f, 0.f);
        if (xr < M) xv = *(const float4*)(xp + k0);
        float4 wv = make_float4(0.f, 0.f, 0.f, 0.f);
        if (wr < N) wv = *(const float4*)(wp + k0);
        Xs[lk + 0][lr] = xv.x; Xs[lk + 1][lr] = xv.y;
        Xs[lk + 2][lr] = xv.z; Xs[lk + 3][lr] = xv.w;
        Ws[lk + 0][lr] = wv.x; Ws[lk + 1][lr] = wv.y;
        Ws[lk + 2][lr] = wv.z; Ws[lk + 3][lr] = wv.w;
        __syncthreads();
        #pragma unroll
        for (int k = 0; k < 16; ++k) {
            float a0 = Xs[k][ty * 4 + 0], a1 = Xs[k][ty * 4 + 1];
            float a2 = Xs[k][ty * 4 + 2], a3 = Xs[k][ty * 4 + 3];
            float b0 = Ws[k][tx * 4 + 0], b1 = Ws[k][tx * 4 + 1];
            float b2 = Ws[k][tx * 4 + 2], b3 = Ws[k][tx * 4 + 3];
            acc[0][0] += a0 * b0; acc[0][1] += a0 * b1; acc[0][2] += a0 * b2; acc[0][3] += a0 * b3;
            acc[1][0] += a1 * b0; acc[1][1] += a1 * b1; acc[1][2] += a1 * b2; acc[1][3] += a1 * b3;
            acc[2][0] += a2 * b0; acc[2][1] += a2 * b1; acc[2][2] += a2 * b2; acc[2][3] += a2 * b3;
            acc[3][0] += a3 * b0; acc[3][1] += a3 * b1; acc[3][2] += a3 * b2; acc[3][3] += a3 * b3;
        }
        __syncthreads();
    }
    const int c0 = bn0 + tx * 4;
    float4 bv = *(const float4*)(bias + c0);
    #pragma unroll
    for (int i = 0; i < 4; ++i) {
        int r = bm0 + ty * 4 + i;
        if (r >= M) continue;
        float4 o;
        o.x = acc[i][0] + bv.x; o.y = acc[i][1] + bv.y;
        o.z = acc[i][2] + bv.z; o.w = acc[i][3] + bv.w;
        if (relu) {
            o.x = fmaxf(o.x, 0.f); o.y = fmaxf(o.y, 0.f);
            o.z = fmaxf(o.z, 0.f); o.w = fmaxf(o.w, 0.f);
        }
        *(float4*)(Y + (size_t)r * N + c0) = o;
    }
}

// ---------------------------------------------------------------------------
// LayerNorm(X + R)*g + b -> fp32 O, optional bf16 Ob, optional bf16 (O+Padd).
// 4 rows/block.
__global__ __launch_bounds__(256)
void ln_res_kernel(const float* __restrict__ X, const float* __restrict__ R,
                   const float* __restrict__ g, const float* __restrict__ bta,
                   float* __restrict__ O, unsigned short* __restrict__ Ob,
                   const float* __restrict__ Padd, unsigned short* __restrict__ Oadd,
                   int nrows)
{
    const int row = blockIdx.x * 4 + (threadIdx.x >> 6);
    if (row >= nrows) return;
    const int t = threadIdx.x & 63;
    const float* x = X + (size_t)row * 256;
    const float* r = R + (size_t)row * 256;
    float v[4];
    float s = 0.f;
    #pragma unroll
    for (int i = 0; i < 4; ++i) { int c = t + 64 * i; v[i] = x[c] + r[c]; s += v[i]; }
    #pragma unroll
    for (int off = 32; off >= 1; off >>= 1) s += __shfl_xor(s, off, 64);
    float mu = s * (1.f / 256.f);
    float s2 = 0.f;
    #pragma unroll
    for (int i = 0; i < 4; ++i) { float d = v[i] - mu; s2 += d * d; }
    #pragma unroll
    for (int off = 32; off >= 1; off >>= 1) s2 += __shfl_xor(s2, off, 64);
    float rstd = rsqrtf(s2 * (1.f / 256.f) + 1e-5f);
    #pragma unroll
    for (int i = 0; i < 4; ++i) {
        int c = t + 64 * i;
        float o = (v[i] - mu) * rstd * g[c] + bta[c];
        O[(size_t)row * 256 + c] = o;
        if (Ob) Ob[(size_t)row * 256 + c] = f2bf(o);
        if (Oadd) Oadd[(size_t)row * 256 + c] = f2bf(o + Padd[(size_t)row * 256 + c]);
    }
}

// ---------------------------------------------------------------------------
// 3D multi-scale deformable attention sampling; fp32 value, bf16 output.
__global__ __launch_bounds__(256)
void deform_kernel(const float* __restrict__ off, const float* __restrict__ awl,
                   const float* __restrict__ value, unsigned short* __restrict__ out)
{
    const int bq = blockIdx.x;
    const int b = bq / S_TOT;
    const int s = bq - b * S_TOT;
    const int t = threadIdx.x;

    __shared__ float aw_sh[128];
    __shared__ float aw_m[8], aw_s[8];
    __shared__ float2 tbl[128][8];
    __shared__ float4 racc[256];

    if (t < 128) aw_sh[t] = awl[(size_t)bq * 128 + t];
    __syncthreads();
    if (t < 8) {
        float m = -1e30f;
        #pragma unroll
        for (int i = 0; i < 16; ++i) m = fmaxf(m, aw_sh[t * 16 + i]);
        float su = 0.f;
        #pragma unroll
        for (int i = 0; i < 16; ++i) su += __expf(aw_sh[t * 16 + i] - m);
        aw_m[t] = m; aw_s[t] = su;
    }
    __syncthreads();

    if (t < 128) {
        const int h = t >> 4, lp = t & 15, l = lp >> 2;
        float aw = __expf(aw_sh[t] - aw_m[h]) / aw_s[h];
        int nq_, sq0;
        if (s < 13824)      { nq_ = 24; sq0 = 0; }
        else if (s < 15552) { nq_ = 12; sq0 = 13824; }
        else if (s < 15768) { nq_ = 6;  sq0 = 15552; }
        else                { nq_ = 3;  sq0 = 15768; }
        int tl = s - sq0;
        int iz = tl / (nq_ * nq_);
        int r1 = tl - iz * nq_ * nq_;
        int iy = r1 / nq_;
        int ix = r1 - iy * nq_;
        float invn = 1.f / (float)nq_;
        float rx = (ix + 0.5f) * invn;
        float ry = (iy + 0.5f) * invn;
        float rz = (iz + 0.5f) * invn;

        const int lvl_n[4]  = {24, 12, 6, 3};
        const int lvl_s0[4] = {0, 13824, 15552, 15768};
        const int nl = lvl_n[l];
        const int s0l = lvl_s0[l];
        const float* op = off + (size_t)bq * 384 + t * 3;
        float x = rx * nl + op[0] - 0.5f;
        float y = ry * nl + op[1] - 0.5f;
        float z = rz * nl + op[2] - 0.5f;
        float fx = floorf(x), fy = floorf(y), fz = floorf(z);
        int x0 = (int)fx, y0 = (int)fy, z0 = (int)fz;
        float wx1 = x - fx, wx0 = 1.f - wx1;
        float wy1 = y - fy, wy0 = 1.f - wy1;
        float wz1 = z - fz, wz0 = 1.f - wz1;
        int xc0 = min(max(x0, 0), nl - 1), xc1 = min(max(x0 + 1, 0), nl - 1);
        int yc0 = min(max(y0, 0), nl - 1), yc1 = min(max(y0 + 1, 0), nl - 1);
        int zc0 = min(max(z0, 0), nl - 1), zc1 = min(max(z0 + 1, 0), nl - 1);
        bool ox0 = (x0 >= 0) && (x0 < nl);
        bool ox1 = (x0 + 1 >= 0) && (x0 + 1 < nl);
        bool oy0 = (y0 >= 0) && (y0 < nl), oy1 = (y0 + 1 >= 0) && (y0 + 1 < nl);
        bool oz0 = (z0 >= 0) && (z0 < nl), oz1 = (z0 + 1 >= 0) && (z0 + 1 < nl);
        int base = b * S_TOT + s0l;
        #pragma unroll
        for (int c = 0; c < 8; ++c) {
            int dx = c & 1, dy = (c >> 1) & 1, dz = c >> 2;
            float w = (dx ? wx1 : wx0) * (dy ? wy1 : wy0) * (dz ? wz1 : wz0);
            bool ok = (dx ? ox1 : ox0) && (dy ? oy1 : oy0) && (dz ? oz1 : oz0);
            int xi = dx ? xc1 : xc0;
            int yi = dy ? yc1 : yc0;
            int zi = dz ? zc1 : zc0;
            int elem = ((base + (zi * nl + yi) * nl + xi) * 8 + h) * 32;
            tbl[t][c] = make_float2(ok ? w * aw : 0.f, __int_as_float(elem));
        }
    }
    __syncthreads();

    const int c4 = t & 7, lpg = (t >> 3) & 3, h2 = t >> 5;
    float4 acc = make_float4(0.f, 0.f, 0.f, 0.f);
    #pragma unroll
    for (int j = 0; j < 4; ++j) {
        const float2* row = tbl[h2 * 16 + lpg * 4 + j];
        #pragma unroll
        for (int c = 0; c < 8; ++c) {
            float2 e = row[c];
            const float4 v = *(const float4*)(value + (size_t)__float_as_int(e.y) + c4 * 4);
            acc.x += e.x * v.x; acc.y += e.x * v.y;
            acc.z += e.x * v.z; acc.w += e.x * v.w;
        }
    }
    racc[t] = acc;
    __syncthreads();
    if (lpg == 0) {
        float4 a = racc[t];
        #pragma unroll
        for (int gg = 1; gg < 4; ++gg) {
            float4 o = racc[t + gg * 8];
            a.x += o.x; a.y += o.y; a.z += o.z; a.w += o.w;
        }
        ushort4 r;
        r.x = f2bf(a.x); r.y = f2bf(a.y); r.z = f2bf(a.z); r.w = f2bf(a.w);
        *(ushort4*)(out + (size_t)bq * 256 + h2 * 32 + c4 * 4) = r;
    }
}

// ---------------------------------------------------------------------------
// small multi-head attention (decoder self-attn, Lk=80), online softmax.
// Q/K may live in a packed [row, 512] buffer -> explicit row strides.
__global__ __launch_bounds__(256)
void attn_kernel(const float* __restrict__ Q, const float* __restrict__ K,
                 const float* __restrict__ V, float* __restrict__ O,
                 int Lq, int Lk, float scale, int ldq, int ldk)
{
    const int nqc = (Lq + 3) >> 2;
    const int blk = blockIdx.x;
    const int qc = blk % nqc;
    const int bh = blk / nqc;
    const int h = bh & 7;
    const int b = bh >> 3;
    const int qi0 = qc * 4;
    const int t = threadIdx.x;
    const int c = t & 31, g = t >> 5;

    float qv[4];
    #pragma unroll
    for (int j = 0; j < 4; ++j)
        qv[j] = Q[((size_t)(b * Lq + qi0 + j)) * ldq + h * 32 + c];

    float m[4], l[4], acc[4];
    #pragma unroll
    for (int j = 0; j < 4; ++j) { m[j] = -1e30f; l[j] = 0.f; acc[j] = 0.f; }

    for (int k = g; k < Lk; k += 8) {
        float kv = K[((size_t)(b * Lk + k)) * ldk + h * 32 + c];
        float vv = V[((size_t)(b * Lk + k)) * 256 + h * 32 + c];
        #pragma unroll
        for (int j = 0; j < 4; ++j) {
            float p = qv[j] * kv;
            p += __shfl_xor(p, 16, 32);
            p += __shfl_xor(p, 8, 32);
            p += __shfl_xor(p, 4, 32);
            p += __shfl_xor(p, 2, 32);
            p += __shfl_xor(p, 1, 32);
            float sc = p * scale;
            float mn = fmaxf(m[j], sc);
            float fo = __expf(m[j] - mn);
            float w = __expf(sc - mn);
            l[j] = l[j] * fo + w;
            acc[j] = acc[j] * fo + w * vv;
            m[j] = mn;
        }
    }
    __shared__ float sm[8][4], sl[8][4], sacc[8][4][32];
    if (c == 0) {
        #pragma unroll
        for (int j = 0; j < 4; ++j) { sm[g][j] = m[j]; sl[g][j] = l[j]; }
    }
    #pragma unroll
    for (int j = 0; j < 4; ++j) sacc[g][j][c] = acc[j];
    __syncthreads();
    if (g == 0) {
        #pragma unroll
        for (int j = 0; j < 4; ++j) {
            float M = -1e30f;
            #pragma unroll
            for (int i = 0; i < 8; ++i) M = fmaxf(M, sm[i][j]);
            float L = 0.f, o = 0.f;
            #pragma unroll
            for (int i = 0; i < 8; ++i) {
                float e = __expf(sm[i][j] - M);
                L += sl[i][j] * e;
                o += sacc[i][j][c] * e;
            }
            O[((size_t)(b * Lq + qi0 + j)) * 256 + h * 32 + c] = o / L;
        }
    }
}

// ---------------------------------------------------------------------------
// split-K flash cross-attention, phase 1 (round-4 proven version).
__global__ __launch_bounds__(256)
void xattn_part_kernel(const float* __restrict__ Q, const float* __restrict__ K,
                       const float* __restrict__ V,
                       const unsigned char* __restrict__ mask,
                       float* __restrict__ pm, float* __restrict__ pl,
                       float* __restrict__ po, int Lk, float scale)
{
    const int split = blockIdx.x;
    const int bh = blockIdx.y;
    const int b = bh >> 3, h = bh & 7;
    const int t = threadIdx.x;
    const int kk = t & 31;
    const int qg = t >> 5;

    __shared__ float Qs[80 * 32];
    __shared__ float Ks[32][33];
    __shared__ float Vs[32][33];
    __shared__ float Ps[80][33];

    for (int i = t; i < 2560; i += 256) {
        int q = i >> 5, c = i & 31;
        Qs[i] = Q[((size_t)(b * NQ + q)) * 256 + h * 32 + c];
    }

    float m[10], l[10], acc[10];
    #pragma unroll
    for (int i = 0; i < 10; ++i) { m[i] = -1e9f; l[i] = 0.f; acc[i] = 0.f; }

    const int k_base = split * XCHUNK;
    for (int k0 = k_base; k0 < k_base + XCHUNK; k0 += 32) {
        __syncthreads();
        {
            int key = t >> 3, c4 = (t & 7) * 4;
            int kg = k0 + key;
            float4 kv = make_float4(0.f, 0.f, 0.f, 0.f);
            float4 vv = make_float4(0.f, 0.f, 0.f, 0.f);
            if (kg < Lk) {
                size_t go = ((size_t)(b * Lk + kg)) * 256 + h * 32 + c4;
                kv = *(const float4*)(K + go);
                vv = *(const float4*)(V + go);
            }
            Ks[key][c4 + 0] = kv.x; Ks[key][c4 + 1] = kv.y;
            Ks[key][c4 + 2] = kv.z; Ks[key][c4 + 3] = kv.w;
            Vs[key][c4 + 0] = vv.x; Vs[key][c4 + 1] = vv.y;
            Vs[key][c4 + 2] = vv.z; Vs[key][c4 + 3] = vv.w;
        }
        __syncthreads();

        float s[10];
        #pragma unroll
        for (int i = 0; i < 10; ++i) s[i] = 0.f;
        #pragma unroll 8
        for (int c = 0; c < 32; ++c) {
            float kv = Ks[kk][c];
            #pragma unroll
            for (int i = 0; i < 10; ++i) s[i] += Qs[(qg * 10 + i) * 32 + c] * kv;
        }
        const int kg = k0 + kk;
        const bool valid = kg < Lk;
        float alpha[10];
        #pragma unroll
        for (int i = 0; i < 10; ++i) {
            const int q = qg * 10 + i;
            float sc = -1e9f;
            if (valid) {
                sc = s[i] * scale;
                if (mask[(size_t)q * Lk + kg]) sc = -1e9f;
            }
            float rm = sc;
            rm = fmaxf(rm, __shfl_xor(rm, 16, 32));
            rm = fmaxf(rm, __shfl_xor(rm, 8, 32));
            rm = fmaxf(rm, __shfl_xor(rm, 4, 32));
            rm = fmaxf(rm, __shfl_xor(rm, 2, 32));
            rm = fmaxf(rm, __shfl_xor(rm, 1, 32));
            float mn = fmaxf(m[i], rm);
            alpha[i] = __expf(m[i] - mn);
            float p = valid ? __expf(sc - mn) : 0.f;
            float ps = p;
            ps += __shfl_xor(ps, 16, 32);
            ps += __shfl_xor(ps, 8, 32);
            ps += __shfl_xor(ps, 4, 32);
            ps += __shfl_xor(ps, 2, 32);
            ps += __shfl_xor(ps, 1, 32);
            l[i] = l[i] * alpha[i] + ps;
            m[i] = mn;
            Ps[q][kk] = p;
        }
        __syncthreads();

        #pragma unroll
        for (int i = 0; i < 10; ++i) acc[i] *= alpha[i];
        #pragma unroll 8
        for (int kj = 0; kj < 32; ++kj) {
            float v = Vs[kj][kk];
            #pragma unroll
            for (int i = 0; i < 10; ++i) acc[i] += Ps[qg * 10 + i][kj] * v;
        }
    }

    const size_t base = ((size_t)bh * XSPLIT + split) * NQ;
    #pragma unroll
    for (int i = 0; i < 10; ++i) {
        const int q = qg * 10 + i;
        if (kk == 0) { pm[base + q] = m[i]; pl[base + q] = l[i]; }
        po[(base + q) * 32 + kk] = acc[i];
    }
}

// phase 2: merge XSPLIT partials per (b,h,q) -> O[B,NQ,256]
__global__ __launch_bounds__(64)
void xattn_merge_kernel(const float* __restrict__ pm, const float* __restrict__ pl,
                        const float* __restrict__ po, float* __restrict__ O)
{
    const int idx = blockIdx.x;
    const int bh = idx / NQ, q = idx - bh * NQ;
    const int b = bh >> 3, h = bh & 7;
    const int tt = threadIdx.x;
    if (tt >= 32) return;
    const int c = tt;
    float M = -1e30f;
    for (int s = 0; s < XSPLIT; ++s)
        M = fmaxf(M, pm[((size_t)bh * XSPLIT + s) * NQ + q]);
    float L = 0.f, o = 0.f;
    for (int s = 0; s < XSPLIT; ++s) {
        size_t base = ((size_t)bh * XSPLIT + s) * NQ + q;
        float e = __expf(pm[base] - M);
        L += pl[base] * e;
        o += po[base * 32 + c] * e;
    }
    O[((size_t)(b * NQ + q)) * 256 + h * 32 + c] = o / L;
}

// ---------------------------------------------------------------------------
extern "C" void kernel_launch(void* const* d_in, const int* in_sizes, int n_in,
                              void* d_out, int out_size, void* d_ws, size_t ws_size,
                              hipStream_t stream)
{
    const float* src       = (const float*)d_in[0];
    const float* pos       = (const float*)d_in[1];
    const float* lvl_pos   = (const float*)d_in[2];
    const float* tgt       = (const float*)d_in[3];
    const float* query_pos = (const float*)d_in[4];
    const float* eow  = (const float*)d_in[6];
    const float* eob  = (const float*)d_in[7];
    const float* eaw  = (const float*)d_in[8];
    const float* eab  = (const float*)d_in[9];
    const float* evw  = (const float*)d_in[10];
    const float* evb  = (const float*)d_in[11];
    const float* eouw = (const float*)d_in[12];
    const float* eoub = (const float*)d_in[13];
    const float* el1g = (const float*)d_in[14];
    const float* el1b = (const float*)d_in[15];
    const float* ef1w = (const float*)d_in[16];
    const float* ef1b = (const float*)d_in[17];
    const float* ef2w = (const float*)d_in[18];
    const float* ef2b = (const float*)d_in[19];
    const float* el2g = (const float*)d_in[20];
    const float* el2b = (const float*)d_in[21];
    const float* dsiw = (const float*)d_in[22];
    const float* dsib = (const float*)d_in[23];
    const float* dsow = (const float*)d_in[24];
    const float* dsob = (const float*)d_in[25];
    const float* dciw = (const float*)d_in[26];
    const float* dcib = (const float*)d_in[27];
    const float* dcow = (const float*)d_in[28];
    const float* dcob = (const float*)d_in[29];
    const float* dl1g = (const float*)d_in[30];
    const float* dl1b = (const float*)d_in[31];
    const float* dl2g = (const float*)d_in[32];
    const float* dl2b = (const float*)d_in[33];
    const float* dl3g = (const float*)d_in[34];
    const float* dl3b = (const float*)d_in[35];
    const float* df1w = (const float*)d_in[36];
    const float* df1b = (const float*)d_in[37];
    const float* df2w = (const float*)d_in[38];
    const float* df2b = (const float*)d_in[39];
    const unsigned char* amask = (const unsigned char*)d_in[40];

    const int MBS = B_SZ * S_TOT;                  // 31590
    const size_t nBSC = (size_t)MBS * 256;
    const size_t nP   = (size_t)MP * 256;
    const size_t nFFA = (size_t)MBS * 384 + (size_t)MBS * 128 + 16384;  // f_off+f_awl+pad

    float* ws = (float*)d_ws;
    float* f_out = ws; ws += nP;                   // encoder state / memory (fp32)
    float* f_mlp = ws; ws += nP;                   // proj output for residual
    float* f_ffa = ws; ws += nFFA;                 // f_off | f_awl ; aliased by b_hs
    float* f_off = f_ffa;                          // MBS*384 (enc offsets ; dec cross-K)
    float* f_awl = f_ffa + (size_t)MBS * 384;      // MBS*128 (enc aw logits)
    float* f_val = ws; ws += nP;                   // enc value / fc2-out ; dec cross-V
    float* d_q   = ws; ws += 40960;
    float* d_qk  = ws; ws += 40960;
    float* d_qkp = ws; ws += 81920;                // packed self-attn Q|K [160,512]
    float* d_sq  = ws; ws += 40960;
    float* d_sv  = ws; ws += 40960;
    float* d_ao  = ws; ws += 40960;
    float* d_pr  = ws; ws += 40960;
    float* d_h   = ws; ws += 163840;
    float* x_pm  = ws; ws += (size_t)16 * XSPLIT * NQ;
    float* x_pl  = ws; ws += (size_t)16 * XSPLIT * NQ;
    float* x_po  = ws; ws += (size_t)16 * XSPLIT * NQ * 32;

    unsigned short* bws = (unsigned short*)ws;
    unsigned short* b_mlp  = bws; bws += nP;            // bf16(state+pos)/dec memory+lvl_pos
    unsigned short* b_out  = bws; bws += nP;            // bf16 encoder state
    unsigned short* w_eow  = bws; bws += (size_t)6 * 384 * 256;
    unsigned short* w_eaw  = bws; bws += (size_t)6 * 128 * 256;
    unsigned short* w_evw  = bws; bws += (size_t)6 * 256 * 256;
    unsigned short* w_eouw = bws; bws += (size_t)6 * 256 * 256;
    unsigned short* w_ef1  = bws; bws += (size_t)6 * 1024 * 256;
    unsigned short* w_ef2  = bws; bws += (size_t)6 * 256 * 1024;
    unsigned short* w_dciw = bws; bws += (size_t)6 * 768 * 256;

    // aliases (disjoint lifetimes, see per-layer op ordering):
    // b_hs (fc1 output, MP*1024 bf16) lives in the f_off/f_awl float region —
    //   f_off/f_awl are dead after deform; b_hs unused in decoder.
    unsigned short* b_hs   = (unsigned short*)f_ffa;
    // b_samp (deform output, MBS*256 bf16) reuses b_mlp — b_mlp is dead between
    //   the off/aw GEMMs and ln2's regeneration of bf16(state+pos).
    unsigned short* b_samp = b_mlp;

    auto gemmb = [&](const unsigned short* A, const unsigned short* W, const float* bb,
                     void* Y, int M, int N, int K, int mode) {
        dim3 grid(N / 128, (M + 127) / 128);
        gemm_bf16_kernel<<<grid, dim3(256), 0, stream>>>(A, W, bb, Y, M, N, K, mode);
    };
    auto gemms = [&](const float* X, const float* W, const float* bb, float* Y,
                     int M, int N, int K, int relu) {
        dim3 grid(N / 64, (M + 63) / 64);
        gemm_bias_kernel<<<grid, dim3(256), 0, stream>>>(X, W, bb, Y, M, N, K, relu);
    };
    auto cast = [&](const float* x, unsigned short* o, size_t n) {
        int n4c = (int)(n / 4);
        cast_bf16_kernel<<<(n4c + 255) / 256, 256, 0, stream>>>(x, o, n4c);
    };

    const int n4 = (int)(nBSC / 4);
    const int dn4 = 40960 / 4;
    const float scale = 0.17677669529663687f;
    const int lnGrid = (MBS + 3) / 4;

    // weight conversions (once per launch)
    cast(eow,  w_eow,  (size_t)6 * 384 * 256);
    cast(eaw,  w_eaw,  (size_t)6 * 128 * 256);
    cast(evw,  w_evw,  (size_t)6 * 256 * 256);
    cast(eouw, w_eouw, (size_t)6 * 256 * 256);
    cast(ef1w, w_ef1,  (size_t)6 * 1024 * 256);
    cast(ef2w, w_ef2,  (size_t)6 * 256 * 1024);
    cast(dciw, w_dciw, (size_t)6 * 768 * 256);

    hipMemcpyAsync(f_out, src, nBSC * sizeof(float), hipMemcpyDeviceToDevice, stream);
    cast(src, b_out, nBSC);
    add_bf16_kernel<<<(n4 + 255) / 256, 256, 0, stream>>>(f_out, pos, b_mlp, n4);

    // ---------------- encoder ----------------
    for (int i = 0; i < 6; ++i) {
        gemmb(b_mlp, w_eow + (size_t)i * 384 * 256, eob + i * 384, f_off, MBS, 384, 256, 0);
        gemmb(b_mlp, w_eaw + (size_t)i * 128 * 256, eab + i * 128, f_awl, MBS, 128, 256, 0);
        gemmb(b_out, w_evw + (size_t)i * 256 * 256, evb + i * 256, f_val, MBS, 256, 256, 0);
        deform_kernel<<<MBS, 256, 0, stream>>>(f_off, f_awl, f_val, b_samp);
        gemmb(b_samp, w_eouw + (size_t)i * 256 * 256, eoub + i * 256, f_mlp, MBS, 256, 256, 0);
        ln_res_kernel<<<lnGrid, 256, 0, stream>>>(f_out, f_mlp, el1g + i * 256, el1b + i * 256,
                                                  f_out, b_out, (const float*)nullptr,
                                                  (unsigned short*)nullptr, MBS);
        // full-size FFN (no chunking); b_hs aliases f_off/f_awl (dead here)
        gemmb(b_out, w_ef1 + (size_t)i * 1024 * 256, ef1b + i * 1024, b_hs, MBS, 1024, 256, 1);
        gemmb(b_hs, w_ef2 + (size_t)i * 256 * 1024, ef2b + i * 256, f_val, MBS, 256, 1024, 0);
        // ln2 also emits bf16(state + pos) for the next layer (lvl_pos after last layer)
        ln_res_kernel<<<lnGrid, 256, 0, stream>>>(f_out, f_val, el2g + i * 256, el2b + i * 256,
                                                  f_out, b_out, (i < 5 ? pos : lvl_pos),
                                                  b_mlp, MBS);
    }

    // ---------------- decoder ----------------
    hipMemcpyAsync(d_q, tgt, 40960 * sizeof(float), hipMemcpyDeviceToDevice, stream);

    for (int i = 0; i < 6; ++i) {
        const float* siw = dsiw + (size_t)i * 768 * 256;
        const float* sib = dsib + (size_t)i * 768;
        add_kernel<<<(dn4 + 255) / 256, 256, 0, stream>>>(d_q, query_pos, d_qk, dn4);
        gemms(d_qk, siw, sib, d_qkp, 160, 512, 256, 0);            // packed Q|K
        gemms(d_q,  siw + 512 * 256, sib + 512, d_sv, 160, 256, 256, 0);
        attn_kernel<<<B_SZ * 8 * (NQ / 4), 256, 0, stream>>>(
            d_qkp, d_qkp + 256, d_sv, d_ao, NQ, NQ, scale, 512, 512);
        gemms(d_ao, dsow + (size_t)i * 256 * 256, dsob + i * 256, d_pr, 160, 256, 256, 0);
        ln_res_kernel<<<40, 256, 0, stream>>>(d_q, d_pr, dl2g + i * 256, dl2b + i * 256,
                                              d_q, (unsigned short*)nullptr,
                                              (const float*)nullptr, (unsigned short*)nullptr, 160);

        const float* cib = dcib + (size_t)i * 768;
        add_kernel<<<(dn4 + 255) / 256, 256, 0, stream>>>(d_q, query_pos, d_qk, dn4);
        gemms(d_qk, dciw + (size_t)i * 768 * 256, cib, d_sq, 160, 256, 256, 0);
        gemmb(b_mlp, w_dciw + (size_t)i * 768 * 256 + 256 * 256, cib + 256,
              f_off, MBS, 256, 256, 0);                                        // cross-K
        gemmb(b_out, w_dciw + (size_t)i * 768 * 256 + 512 * 256, cib + 512,
              f_val, MBS, 256, 256, 0);                                        // cross-V
        xattn_part_kernel<<<dim3(XSPLIT, 16), 256, 0, stream>>>(
            d_sq, f_off, f_val, amask, x_pm, x_pl, x_po, S_TOT, scale);
        xattn_merge_kernel<<<16 * NQ, 64, 0, stream>>>(x_pm, x_pl, x_po, d_ao);
        gemms(d_ao, dcow + (size_t)i * 256 * 256, dcob + i * 256, d_pr, 160, 256, 256, 0);
        ln_res_kernel<<<40, 256, 0, stream>>>(d_q, d_pr, dl1g + i * 256, dl1b + i * 256,
                                              d_q, (unsigned short*)nullptr,
                                              (const float*)nullptr, (unsigned short*)nullptr, 160);

        gemms(d_q, df1w + (size_t)i * 1024 * 256, df1b + i * 1024, d_h, 160, 1024, 256, 1);
        gemms(d_h, df2w + (size_t)i * 256 * 1024, df2b + i * 256, d_pr, 160, 256, 1024, 0);
        ln_res_kernel<<<40, 256, 0, stream>>>(d_q, d_pr, dl3g + i * 256, dl3b + i * 256,
                                              d_q, (unsigned short*)nullptr,
                                              (const float*)nullptr, (unsigned short*)nullptr, 160);
    }

    hipMemcpyAsync(d_out, d_q, 40960 * sizeof(float), hipMemcpyDeviceToDevice, stream);
}

// Round 11
// 4985.584 us; speedup vs baseline: 1.2359x; 1.0024x over previous
//
#include <hip/hip_runtime.h>
#include <cstdint>

#define S_TOT 15795
#define B_SZ 2
#define NQ 80
#define XSPLIT 128
#define XCHUNK 128
#define MP 31616          // 31590 padded to multiple of 128

typedef __attribute__((ext_vector_type(8))) short short8;
typedef __attribute__((ext_vector_type(4))) float f32x4;

__device__ __forceinline__ unsigned short f2bf(float f) {
    unsigned u = __float_as_uint(f);
    unsigned r = u + 0x7fffu + ((u >> 16) & 1u);
    return (unsigned short)(r >> 16);
}

// ---------------------------------------------------------------------------
__global__ __launch_bounds__(256)
void cast_bf16_kernel(const float* __restrict__ x, unsigned short* __restrict__ o, int n4)
{
    int i = blockIdx.x * 256 + threadIdx.x;
    if (i < n4) {
        float4 v = ((const float4*)x)[i];
        ushort4 r;
        r.x = f2bf(v.x); r.y = f2bf(v.y); r.z = f2bf(v.z); r.w = f2bf(v.w);
        ((ushort4*)o)[i] = r;
    }
}

// elementwise add, fp32 out
__global__ __launch_bounds__(256)
void add_kernel(const float* __restrict__ a, const float* __restrict__ b,
                float* __restrict__ o, int n4)
{
    int i = blockIdx.x * 256 + threadIdx.x;
    if (i < n4) {
        float4 av = ((const float4*)a)[i];
        float4 bv = ((const float4*)b)[i];
        float4 ov;
        ov.x = av.x + bv.x; ov.y = av.y + bv.y;
        ov.z = av.z + bv.z; ov.w = av.w + bv.w;
        ((float4*)o)[i] = ov;
    }
}

// elementwise add, bf16 out
__global__ __launch_bounds__(256)
void add_bf16_kernel(const float* __restrict__ a, const float* __restrict__ b,
                     unsigned short* __restrict__ o, int n4)
{
    int i = blockIdx.x * 256 + threadIdx.x;
    if (i < n4) {
        float4 av = ((const float4*)a)[i];
        float4 bv = ((const float4*)b)[i];
        ushort4 r;
        r.x = f2bf(av.x + bv.x); r.y = f2bf(av.y + bv.y);
        r.z = f2bf(av.z + bv.z); r.w = f2bf(av.w + bv.w);
        ((ushort4*)o)[i] = r;
    }
}

// ---------------------------------------------------------------------------
// pure-bf16 MFMA GEMM, register-staged DOUBLE-BUFFERED LDS (1 barrier/K-step).
// Y[M,N] = A[M,K](bf16) @ B[N,K](bf16)^T + bias.
// mode 0: fp32 out; 1: relu + bf16 out; 2: bf16 out (no relu).
// A readable to round-up-128(M) rows; N%128==0, K%32==0.
__global__ __launch_bounds__(256)
void gemm_bf16_kernel(const unsigned short* __restrict__ A,
                      const unsigned short* __restrict__ B,
                      const float* __restrict__ bias, void* __restrict__ Yv,
                      int M, int N, int K, int mode)
{
    __shared__ unsigned short As[2][128 * 32];
    __shared__ unsigned short Bs[2][128 * 32];
    const int t = threadIdx.x;
    const int wave = t >> 6, lane = t & 63;
    const int quad = lane >> 4, l16 = lane & 15;
    const int bm0 = blockIdx.y * 128;
    const int bn0 = blockIdx.x * 128;
    const int wm = (wave & 1) * 64;
    const int wn = (wave >> 1) * 64;
    const int srow = t >> 2;          // 0..63
    const int scol = (t & 3) * 8;     // 0,8,16,24

    f32x4 acc[4][4] = {};

    const unsigned short* pa0 = A + (size_t)(bm0 + srow) * K + scol;
    const unsigned short* pa1 = pa0 + (size_t)64 * K;
    const unsigned short* pb0 = B + (size_t)(bn0 + srow) * K + scol;
    const unsigned short* pb1 = pb0 + (size_t)64 * K;

    const int nk = K / 32;
    short8 a0 = *(const short8*)(pa0);
    short8 a1 = *(const short8*)(pa1);
    short8 b0 = *(const short8*)(pb0);
    short8 b1 = *(const short8*)(pb1);
    *(short8*)&As[0][srow * 32 + scol] = a0;
    *(short8*)&As[0][(srow + 64) * 32 + scol] = a1;
    *(short8*)&Bs[0][srow * 32 + scol] = b0;
    *(short8*)&Bs[0][(srow + 64) * 32 + scol] = b1;
    __syncthreads();

    for (int kb = 0; kb < nk; ++kb) {
        const int cur = kb & 1, nxt = cur ^ 1;
        const bool more = (kb + 1) < nk;
        if (more) {
            const int k0 = (kb + 1) * 32;
            a0 = *(const short8*)(pa0 + k0);
            a1 = *(const short8*)(pa1 + k0);
            b0 = *(const short8*)(pb0 + k0);
            b1 = *(const short8*)(pb1 + k0);
        }

        short8 af[4], bf[4];
        #pragma unroll
        for (int im = 0; im < 4; ++im)
            af[im] = *(const short8*)&As[cur][(wm + im * 16 + l16) * 32 + quad * 8];
        #pragma unroll
        for (int in = 0; in < 4; ++in)
            bf[in] = *(const short8*)&Bs[cur][(wn + in * 16 + l16) * 32 + quad * 8];
        #pragma unroll
        for (int im = 0; im < 4; ++im)
            #pragma unroll
            for (int in = 0; in < 4; ++in)
                acc[im][in] = __builtin_amdgcn_mfma_f32_16x16x32_bf16(
                    af[im], bf[in], acc[im][in], 0, 0, 0);

        if (more) {
            *(short8*)&As[nxt][srow * 32 + scol] = a0;
            *(short8*)&As[nxt][(srow + 64) * 32 + scol] = a1;
            *(short8*)&Bs[nxt][srow * 32 + scol] = b0;
            *(short8*)&Bs[nxt][(srow + 64) * 32 + scol] = b1;
        }
        __syncthreads();
    }

    // C/D: row = quad*4 + reg, col = l16
    #pragma unroll
    for (int im = 0; im < 4; ++im) {
        const int gm0 = bm0 + wm + im * 16 + quad * 4;
        #pragma unroll
        for (int in = 0; in < 4; ++in) {
            const int gn = bn0 + wn + in * 16 + l16;
            const float bv = bias[gn];
            #pragma unroll
            for (int r = 0; r < 4; ++r) {
                int row = gm0 + r;
                if (row < M) {
                    float o = acc[im][in][r] + bv;
                    if (mode == 0) {
                        ((float*)Yv)[(size_t)row * N + gn] = o;
                    } else {
                        if (mode == 1) o = fmaxf(o, 0.f);
                        ((unsigned short*)Yv)[(size_t)row * N + gn] = f2bf(o);
                    }
                }
            }
        }
    }
}

// ---------------------------------------------------------------------------
// fp32 GEMM for small decoder matrices. K%16==0, N%64==0.
__global__ __launch_bounds__(256)
void gemm_bias_kernel(const float* __restrict__ X, const float* __restrict__ W,
                      const float* __restrict__ bias, float* __restrict__ Y,
                      int M, int N, int K, int relu)
{
    __shared__ float Xs[16][68];
    __shared__ float Ws[16][68];
    const int bm0 = blockIdx.y * 64;
    const int bn0 = blockIdx.x * 64;
    const int t = threadIdx.x;
    const int tx = t & 15, ty = t >> 4;
    const int lr = t >> 2;
    const int lk = (t & 3) << 2;
    float acc[4][4] = {};
    const int xr = bm0 + lr;
    const int wr = bn0 + lr;
    const float* xp = X + (size_t)xr * K + lk;
    const float* wp = W + (size_t)wr * K + lk;
    for (int k0 = 0; k0 < K; k0 += 16) {
        float4 xv = make_float4(0.f, 0.f, 0.f, 0.f);
        if (xr < M) xv = *(const float4*)(xp + k0);
        float4 wv = make_float4(0.f, 0.f, 0.f, 0.f);
        if (wr < N) wv = *(const float4*)(wp + k0);
        Xs[lk + 0][lr] = xv.x; Xs[lk + 1][lr] = xv.y;
        Xs[lk + 2][lr] = xv.z; Xs[lk + 3][lr] = xv.w;
        Ws[lk + 0][lr] = wv.x; Ws[lk + 1][lr] = wv.y;
        Ws[lk + 2][lr] = wv.z; Ws[lk + 3][lr] = wv.w;
        __syncthreads();
        #pragma unroll
        for (int k = 0; k < 16; ++k) {
            float a0 = Xs[k][ty * 4 + 0], a1 = Xs[k][ty * 4 + 1];
            float a2 = Xs[k][ty * 4 + 2], a3 = Xs[k][ty * 4 + 3];
            float b0 = Ws[k][tx * 4 + 0], b1 = Ws[k][tx * 4 + 1];
            float b2 = Ws[k][tx * 4 + 2], b3 = Ws[k][tx * 4 + 3];
            acc[0][0] += a0 * b0; acc[0][1] += a0 * b1; acc[0][2] += a0 * b2; acc[0][3] += a0 * b3;
            acc[1][0] += a1 * b0; acc[1][1] += a1 * b1; acc[1][2] += a1 * b2; acc[1][3] += a1 * b3;
            acc[2][0] += a2 * b0; acc[2][1] += a2 * b1; acc[2][2] += a2 * b2; acc[2][3] += a2 * b3;
            acc[3][0] += a3 * b0; acc[3][1] += a3 * b1; acc[3][2] += a3 * b2; acc[3][3] += a3 * b3;
        }
        __syncthreads();
    }
    const int c0 = bn0 + tx * 4;
    float4 bv = *(const float4*)(bias + c0);
    #pragma unroll
    for (int i = 0; i < 4; ++i) {
        int r = bm0 + ty * 4 + i;
        if (r >= M) continue;
        float4 o;
        o.x = acc[i][0] + bv.x; o.y = acc[i][1] + bv.y;
        o.z = acc[i][2] + bv.z; o.w = acc[i][3] + bv.w;
        if (relu) {
            o.x = fmaxf(o.x, 0.f); o.y = fmaxf(o.y, 0.f);
            o.z = fmaxf(o.z, 0.f); o.w = fmaxf(o.w, 0.f);
        }
        *(float4*)(Y + (size_t)r * N + c0) = o;
    }
}

// ---------------------------------------------------------------------------
// LayerNorm(X + R)*g + b -> fp32 O, optional bf16 Ob, optional bf16 (O+Padd).
// 4 rows/block.
__global__ __launch_bounds__(256)
void ln_res_kernel(const float* __restrict__ X, const float* __restrict__ R,
                   const float* __restrict__ g, const float* __restrict__ bta,
                   float* __restrict__ O, unsigned short* __restrict__ Ob,
                   const float* __restrict__ Padd, unsigned short* __restrict__ Oadd,
                   int nrows)
{
    const int row = blockIdx.x * 4 + (threadIdx.x >> 6);
    if (row >= nrows) return;
    const int t = threadIdx.x & 63;
    const float* x = X + (size_t)row * 256;
    const float* r = R + (size_t)row * 256;
    float v[4];
    float s = 0.f;
    #pragma unroll
    for (int i = 0; i < 4; ++i) { int c = t + 64 * i; v[i] = x[c] + r[c]; s += v[i]; }
    #pragma unroll
    for (int off = 32; off >= 1; off >>= 1) s += __shfl_xor(s, off, 64);
    float mu = s * (1.f / 256.f);
    float s2 = 0.f;
    #pragma unroll
    for (int i = 0; i < 4; ++i) { float d = v[i] - mu; s2 += d * d; }
    #pragma unroll
    for (int off = 32; off >= 1; off >>= 1) s2 += __shfl_xor(s2, off, 64);
    float rstd = rsqrtf(s2 * (1.f / 256.f) + 1e-5f);
    #pragma unroll
    for (int i = 0; i < 4; ++i) {
        int c = t + 64 * i;
        float o = (v[i] - mu) * rstd * g[c] + bta[c];
        O[(size_t)row * 256 + c] = o;
        if (Ob) Ob[(size_t)row * 256 + c] = f2bf(o);
        if (Oadd) Oadd[(size_t)row * 256 + c] = f2bf(o + Padd[(size_t)row * 256 + c]);
    }
}

// ---------------------------------------------------------------------------
// 3D multi-scale deformable attention sampling; fp32 value, bf16 output.
__global__ __launch_bounds__(256)
void deform_kernel(const float* __restrict__ off, const float* __restrict__ awl,
                   const float* __restrict__ value, unsigned short* __restrict__ out)
{
    const int bq = blockIdx.x;
    const int b = bq / S_TOT;
    const int s = bq - b * S_TOT;
    const int t = threadIdx.x;

    __shared__ float aw_sh[128];
    __shared__ float aw_m[8], aw_s[8];
    __shared__ float2 tbl[128][8];
    __shared__ float4 racc[256];

    if (t < 128) aw_sh[t] = awl[(size_t)bq * 128 + t];
    __syncthreads();
    if (t < 8) {
        float m = -1e30f;
        #pragma unroll
        for (int i = 0; i < 16; ++i) m = fmaxf(m, aw_sh[t * 16 + i]);
        float su = 0.f;
        #pragma unroll
        for (int i = 0; i < 16; ++i) su += __expf(aw_sh[t * 16 + i] - m);
        aw_m[t] = m; aw_s[t] = su;
    }
    __syncthreads();

    if (t < 128) {
        const int h = t >> 4, lp = t & 15, l = lp >> 2;
        float aw = __expf(aw_sh[t] - aw_m[h]) / aw_s[h];
        int nq_, sq0;
        if (s < 13824)      { nq_ = 24; sq0 = 0; }
        else if (s < 15552) { nq_ = 12; sq0 = 13824; }
        else if (s < 15768) { nq_ = 6;  sq0 = 15552; }
        else                { nq_ = 3;  sq0 = 15768; }
        int tl = s - sq0;
        int iz = tl / (nq_ * nq_);
        int r1 = tl - iz * nq_ * nq_;
        int iy = r1 / nq_;
        int ix = r1 - iy * nq_;
        float invn = 1.f / (float)nq_;
        float rx = (ix + 0.5f) * invn;
        float ry = (iy + 0.5f) * invn;
        float rz = (iz + 0.5f) * invn;

        const int lvl_n[4]  = {24, 12, 6, 3};
        const int lvl_s0[4] = {0, 13824, 15552, 15768};
        const int nl = lvl_n[l];
        const int s0l = lvl_s0[l];
        const float* op = off + (size_t)bq * 384 + t * 3;
        float x = rx * nl + op[0] - 0.5f;
        float y = ry * nl + op[1] - 0.5f;
        float z = rz * nl + op[2] - 0.5f;
        float fx = floorf(x), fy = floorf(y), fz = floorf(z);
        int x0 = (int)fx, y0 = (int)fy, z0 = (int)fz;
        float wx1 = x - fx, wx0 = 1.f - wx1;
        float wy1 = y - fy, wy0 = 1.f - wy1;
        float wz1 = z - fz, wz0 = 1.f - wz1;
        int xc0 = min(max(x0, 0), nl - 1), xc1 = min(max(x0 + 1, 0), nl - 1);
        int yc0 = min(max(y0, 0), nl - 1), yc1 = min(max(y0 + 1, 0), nl - 1);
        int zc0 = min(max(z0, 0), nl - 1), zc1 = min(max(z0 + 1, 0), nl - 1);
        bool ox0 = (x0 >= 0) && (x0 < nl);
        bool ox1 = (x0 + 1 >= 0) && (x0 + 1 < nl);
        bool oy0 = (y0 >= 0) && (y0 < nl), oy1 = (y0 + 1 >= 0) && (y0 + 1 < nl);
        bool oz0 = (z0 >= 0) && (z0 < nl), oz1 = (z0 + 1 >= 0) && (z0 + 1 < nl);
        int base = b * S_TOT + s0l;
        #pragma unroll
        for (int c = 0; c < 8; ++c) {
            int dx = c & 1, dy = (c >> 1) & 1, dz = c >> 2;
            float w = (dx ? wx1 : wx0) * (dy ? wy1 : wy0) * (dz ? wz1 : wz0);
            bool ok = (dx ? ox1 : ox0) && (dy ? oy1 : oy0) && (dz ? oz1 : oz0);
            int xi = dx ? xc1 : xc0;
            int yi = dy ? yc1 : yc0;
            int zi = dz ? zc1 : zc0;
            int elem = ((base + (zi * nl + yi) * nl + xi) * 8 + h) * 32;
            tbl[t][c] = make_float2(ok ? w * aw : 0.f, __int_as_float(elem));
        }
    }
    __syncthreads();

    const int c4 = t & 7, lpg = (t >> 3) & 3, h2 = t >> 5;
    float4 acc = make_float4(0.f, 0.f, 0.f, 0.f);
    #pragma unroll
    for (int j = 0; j < 4; ++j) {
        const float2* row = tbl[h2 * 16 + lpg * 4 + j];
        #pragma unroll
        for (int c = 0; c < 8; ++c) {
            float2 e = row[c];
            const float4 v = *(const float4*)(value + (size_t)__float_as_int(e.y) + c4 * 4);
            acc.x += e.x * v.x; acc.y += e.x * v.y;
            acc.z += e.x * v.z; acc.w += e.x * v.w;
        }
    }
    racc[t] = acc;
    __syncthreads();
    if (lpg == 0) {
        float4 a = racc[t];
        #pragma unroll
        for (int gg = 1; gg < 4; ++gg) {
            float4 o = racc[t + gg * 8];
            a.x += o.x; a.y += o.y; a.z += o.z; a.w += o.w;
        }
        ushort4 r;
        r.x = f2bf(a.x); r.y = f2bf(a.y); r.z = f2bf(a.z); r.w = f2bf(a.w);
        *(ushort4*)(out + (size_t)bq * 256 + h2 * 32 + c4 * 4) = r;
    }
}

// ---------------------------------------------------------------------------
// small multi-head attention (decoder self-attn, Lk=80), online softmax.
// Q/K may live in a packed [row, 512] buffer -> explicit row strides.
__global__ __launch_bounds__(256)
void attn_kernel(const float* __restrict__ Q, const float* __restrict__ K,
                 const float* __restrict__ V, float* __restrict__ O,
                 int Lq, int Lk, float scale, int ldq, int ldk)
{
    const int nqc = (Lq + 3) >> 2;
    const int blk = blockIdx.x;
    const int qc = blk % nqc;
    const int bh = blk / nqc;
    const int h = bh & 7;
    const int b = bh >> 3;
    const int qi0 = qc * 4;
    const int t = threadIdx.x;
    const int c = t & 31, g = t >> 5;

    float qv[4];
    #pragma unroll
    for (int j = 0; j < 4; ++j)
        qv[j] = Q[((size_t)(b * Lq + qi0 + j)) * ldq + h * 32 + c];

    float m[4], l[4], acc[4];
    #pragma unroll
    for (int j = 0; j < 4; ++j) { m[j] = -1e30f; l[j] = 0.f; acc[j] = 0.f; }

    for (int k = g; k < Lk; k += 8) {
        float kv = K[((size_t)(b * Lk + k)) * ldk + h * 32 + c];
        float vv = V[((size_t)(b * Lk + k)) * 256 + h * 32 + c];
        #pragma unroll
        for (int j = 0; j < 4; ++j) {
            float p = qv[j] * kv;
            p += __shfl_xor(p, 16, 32);
            p += __shfl_xor(p, 8, 32);
            p += __shfl_xor(p, 4, 32);
            p += __shfl_xor(p, 2, 32);
            p += __shfl_xor(p, 1, 32);
            float sc = p * scale;
            float mn = fmaxf(m[j], sc);
            float fo = __expf(m[j] - mn);
            float w = __expf(sc - mn);
            l[j] = l[j] * fo + w;
            acc[j] = acc[j] * fo + w * vv;
            m[j] = mn;
        }
    }
    __shared__ float sm[8][4], sl[8][4], sacc[8][4][32];
    if (c == 0) {
        #pragma unroll
        for (int j = 0; j < 4; ++j) { sm[g][j] = m[j]; sl[g][j] = l[j]; }
    }
    #pragma unroll
    for (int j = 0; j < 4; ++j) sacc[g][j][c] = acc[j];
    __syncthreads();
    if (g == 0) {
        #pragma unroll
        for (int j = 0; j < 4; ++j) {
            float M = -1e30f;
            #pragma unroll
            for (int i = 0; i < 8; ++i) M = fmaxf(M, sm[i][j]);
            float L = 0.f, o = 0.f;
            #pragma unroll
            for (int i = 0; i < 8; ++i) {
                float e = __expf(sm[i][j] - M);
                L += sl[i][j] * e;
                o += sacc[i][j][c] * e;
            }
            O[((size_t)(b * Lq + qi0 + j)) * 256 + h * 32 + c] = o / L;
        }
    }
}

// ---------------------------------------------------------------------------
// split-K flash cross-attention, phase 1 (proven structure; XCHUNK=128).
__global__ __launch_bounds__(256)
void xattn_part_kernel(const float* __restrict__ Q, const float* __restrict__ K,
                       const float* __restrict__ V,
                       const unsigned char* __restrict__ mask,
                       float* __restrict__ pm, float* __restrict__ pl,
                       float* __restrict__ po, int Lk, float scale)
{
    const int split = blockIdx.x;
    const int bh = blockIdx.y;
    const int b = bh >> 3, h = bh & 7;
    const int t = threadIdx.x;
    const int kk = t & 31;
    const int qg = t >> 5;

    __shared__ float Qs[80 * 32];
    __shared__ float Ks[32][33];
    __shared__ float Vs[32][33];
    __shared__ float Ps[80][33];

    for (int i = t; i < 2560; i += 256) {
        int q = i >> 5, c = i & 31;
        Qs[i] = Q[((size_t)(b * NQ + q)) * 256 + h * 32 + c];
    }

    float m[10], l[10], acc[10];
    #pragma unroll
    for (int i = 0; i < 10; ++i) { m[i] = -1e9f; l[i] = 0.f; acc[i] = 0.f; }

    const int k_base = split * XCHUNK;
    for (int k0 = k_base; k0 < k_base + XCHUNK; k0 += 32) {
        __syncthreads();
        {
            int key = t >> 3, c4 = (t & 7) * 4;
            int kg = k0 + key;
            float4 kv = make_float4(0.f, 0.f, 0.f, 0.f);
            float4 vv = make_float4(0.f, 0.f, 0.f, 0.f);
            if (kg < Lk) {
                size_t go = ((size_t)(b * Lk + kg)) * 256 + h * 32 + c4;
                kv = *(const float4*)(K + go);
                vv = *(const float4*)(V + go);
            }
            Ks[key][c4 + 0] = kv.x; Ks[key][c4 + 1] = kv.y;
            Ks[key][c4 + 2] = kv.z; Ks[key][c4 + 3] = kv.w;
            Vs[key][c4 + 0] = vv.x; Vs[key][c4 + 1] = vv.y;
            Vs[key][c4 + 2] = vv.z; Vs[key][c4 + 3] = vv.w;
        }
        __syncthreads();

        float s[10];
        #pragma unroll
        for (int i = 0; i < 10; ++i) s[i] = 0.f;
        #pragma unroll 8
        for (int c = 0; c < 32; ++c) {
            float kv = Ks[kk][c];
            #pragma unroll
            for (int i = 0; i < 10; ++i) s[i] += Qs[(qg * 10 + i) * 32 + c] * kv;
        }
        const int kg = k0 + kk;
        const bool valid = kg < Lk;
        float alpha[10];
        #pragma unroll
        for (int i = 0; i < 10; ++i) {
            const int q = qg * 10 + i;
            float sc = -1e9f;
            if (valid) {
                sc = s[i] * scale;
                if (mask[(size_t)q * Lk + kg]) sc = -1e9f;
            }
            float rm = sc;
            rm = fmaxf(rm, __shfl_xor(rm, 16, 32));
            rm = fmaxf(rm, __shfl_xor(rm, 8, 32));
            rm = fmaxf(rm, __shfl_xor(rm, 4, 32));
            rm = fmaxf(rm, __shfl_xor(rm, 2, 32));
            rm = fmaxf(rm, __shfl_xor(rm, 1, 32));
            float mn = fmaxf(m[i], rm);
            alpha[i] = __expf(m[i] - mn);
            float p = valid ? __expf(sc - mn) : 0.f;
            float ps = p;
            ps += __shfl_xor(ps, 16, 32);
            ps += __shfl_xor(ps, 8, 32);
            ps += __shfl_xor(ps, 4, 32);
            ps += __shfl_xor(ps, 2, 32);
            ps += __shfl_xor(ps, 1, 32);
            l[i] = l[i] * alpha[i] + ps;
            m[i] = mn;
            Ps[q][kk] = p;
        }
        __syncthreads();

        #pragma unroll
        for (int i = 0; i < 10; ++i) acc[i] *= alpha[i];
        #pragma unroll 8
        for (int kj = 0; kj < 32; ++kj) {
            float v = Vs[kj][kk];
            #pragma unroll
            for (int i = 0; i < 10; ++i) acc[i] += Ps[qg * 10 + i][kj] * v;
        }
    }

    const size_t base = ((size_t)bh * XSPLIT + split) * NQ;
    #pragma unroll
    for (int i = 0; i < 10; ++i) {
        const int q = qg * 10 + i;
        if (kk == 0) { pm[base + q] = m[i]; pl[base + q] = l[i]; }
        po[(base + q) * 32 + kk] = acc[i];
    }
}

// phase 2: merge XSPLIT partials per (b,h,q) -> O[B,NQ,256]
__global__ __launch_bounds__(64)
void xattn_merge_kernel(const float* __restrict__ pm, const float* __restrict__ pl,
                        const float* __restrict__ po, float* __restrict__ O)
{
    const int idx = blockIdx.x;
    const int bh = idx / NQ, q = idx - bh * NQ;
    const int b = bh >> 3, h = bh & 7;
    const int tt = threadIdx.x;
    if (tt >= 32) return;
    const int c = tt;
    float M = -1e30f;
    for (int s = 0; s < XSPLIT; ++s)
        M = fmaxf(M, pm[((size_t)bh * XSPLIT + s) * NQ + q]);
    float L = 0.f, o = 0.f;
    for (int s = 0; s < XSPLIT; ++s) {
        size_t base = ((size_t)bh * XSPLIT + s) * NQ + q;
        float e = __expf(pm[base] - M);
        L += pl[base] * e;
        o += po[base * 32 + c] * e;
    }
    O[((size_t)(b * NQ + q)) * 256 + h * 32 + c] = o / L;
}

// ---------------------------------------------------------------------------
extern "C" void kernel_launch(void* const* d_in, const int* in_sizes, int n_in,
                              void* d_out, int out_size, void* d_ws, size_t ws_size,
                              hipStream_t stream)
{
    const float* src       = (const float*)d_in[0];
    const float* pos       = (const float*)d_in[1];
    const float* lvl_pos   = (const float*)d_in[2];
    const float* tgt       = (const float*)d_in[3];
    const float* query_pos = (const float*)d_in[4];
    const float* eow  = (const float*)d_in[6];
    const float* eob  = (const float*)d_in[7];
    const float* eaw  = (const float*)d_in[8];
    const float* eab  = (const float*)d_in[9];
    const float* evw  = (const float*)d_in[10];
    const float* evb  = (const float*)d_in[11];
    const float* eouw = (const float*)d_in[12];
    const float* eoub = (const float*)d_in[13];
    const float* el1g = (const float*)d_in[14];
    const float* el1b = (const float*)d_in[15];
    const float* ef1w = (const float*)d_in[16];
    const float* ef1b = (const float*)d_in[17];
    const float* ef2w = (const float*)d_in[18];
    const float* ef2b = (const float*)d_in[19];
    const float* el2g = (const float*)d_in[20];
    const float* el2b = (const float*)d_in[21];
    const float* dsiw = (const float*)d_in[22];
    const float* dsib = (const float*)d_in[23];
    const float* dsow = (const float*)d_in[24];
    const float* dsob = (const float*)d_in[25];
    const float* dciw = (const float*)d_in[26];
    const float* dcib = (const float*)d_in[27];
    const float* dcow = (const float*)d_in[28];
    const float* dcob = (const float*)d_in[29];
    const float* dl1g = (const float*)d_in[30];
    const float* dl1b = (const float*)d_in[31];
    const float* dl2g = (const float*)d_in[32];
    const float* dl2b = (const float*)d_in[33];
    const float* dl3g = (const float*)d_in[34];
    const float* dl3b = (const float*)d_in[35];
    const float* df1w = (const float*)d_in[36];
    const float* df1b = (const float*)d_in[37];
    const float* df2w = (const float*)d_in[38];
    const float* df2b = (const float*)d_in[39];
    const unsigned char* amask = (const unsigned char*)d_in[40];

    const int MBS = B_SZ * S_TOT;                  // 31590
    const size_t nBSC = (size_t)MBS * 256;
    const size_t nP   = (size_t)MP * 256;
    const size_t nFFA = (size_t)MBS * 384 + (size_t)MBS * 128 + 16384;  // f_off+f_awl+pad

    float* ws = (float*)d_ws;
    float* f_out = ws; ws += nP;                   // encoder state / memory (fp32)
    float* f_mlp = ws; ws += nP;                   // proj output for residual
    float* f_ffa = ws; ws += nFFA;                 // f_off | f_awl ; aliased by b_hs
    float* f_off = f_ffa;                          // MBS*384 (enc offsets ; dec cross-K)
    float* f_awl = f_ffa + (size_t)MBS * 384;      // MBS*128 (enc aw logits)
    float* f_val = ws; ws += nP;                   // enc value / fc2-out ; dec cross-V
    float* d_q   = ws; ws += 40960;
    float* d_qk  = ws; ws += 40960;
    float* d_qkp = ws; ws += 81920;                // packed self-attn Q|K [160,512]
    float* d_sq  = ws; ws += 40960;
    float* d_sv  = ws; ws += 40960;
    float* d_ao  = ws; ws += 40960;
    float* d_pr  = ws; ws += 40960;
    float* d_h   = ws; ws += 163840;
    float* x_pm  = ws; ws += (size_t)16 * XSPLIT * NQ;
    float* x_pl  = ws; ws += (size_t)16 * XSPLIT * NQ;
    float* x_po  = ws; ws += (size_t)16 * XSPLIT * NQ * 32;

    unsigned short* bws = (unsigned short*)ws;
    unsigned short* b_mlp  = bws; bws += nP;            // bf16(state+pos)/dec memory+lvl_pos
    unsigned short* b_out  = bws; bws += nP;            // bf16 encoder state
    unsigned short* w_eow  = bws; bws += (size_t)6 * 384 * 256;
    unsigned short* w_eaw  = bws; bws += (size_t)6 * 128 * 256;
    unsigned short* w_evw  = bws; bws += (size_t)6 * 256 * 256;
    unsigned short* w_eouw = bws; bws += (size_t)6 * 256 * 256;
    unsigned short* w_ef1  = bws; bws += (size_t)6 * 1024 * 256;
    unsigned short* w_ef2  = bws; bws += (size_t)6 * 256 * 1024;
    unsigned short* w_dciw = bws; bws += (size_t)6 * 768 * 256;

    // aliases (disjoint lifetimes):
    unsigned short* b_hs   = (unsigned short*)f_ffa;   // fc1 out (MP*1024 bf16)
    unsigned short* b_samp = b_mlp;                    // deform out (MBS*256 bf16)

    auto gemmb = [&](const unsigned short* A, const unsigned short* W, const float* bb,
                     void* Y, int M, int N, int K, int mode) {
        dim3 grid(N / 128, (M + 127) / 128);
        gemm_bf16_kernel<<<grid, dim3(256), 0, stream>>>(A, W, bb, Y, M, N, K, mode);
    };
    auto gemms = [&](const float* X, const float* W, const float* bb, float* Y,
                     int M, int N, int K, int relu) {
        dim3 grid(N / 64, (M + 63) / 64);
        gemm_bias_kernel<<<grid, dim3(256), 0, stream>>>(X, W, bb, Y, M, N, K, relu);
    };
    auto cast = [&](const float* x, unsigned short* o, size_t n) {
        int n4c = (int)(n / 4);
        cast_bf16_kernel<<<(n4c + 255) / 256, 256, 0, stream>>>(x, o, n4c);
    };

    const int n4 = (int)(nBSC / 4);
    const int dn4 = 40960 / 4;
    const float scale = 0.17677669529663687f;
    const int lnGrid = (MBS + 3) / 4;

    // weight conversions (once per launch)
    cast(eow,  w_eow,  (size_t)6 * 384 * 256);
    cast(eaw,  w_eaw,  (size_t)6 * 128 * 256);
    cast(evw,  w_evw,  (size_t)6 * 256 * 256);
    cast(eouw, w_eouw, (size_t)6 * 256 * 256);
    cast(ef1w, w_ef1,  (size_t)6 * 1024 * 256);
    cast(ef2w, w_ef2,  (size_t)6 * 256 * 1024);
    cast(dciw, w_dciw, (size_t)6 * 768 * 256);

    hipMemcpyAsync(f_out, src, nBSC * sizeof(float), hipMemcpyDeviceToDevice, stream);
    cast(src, b_out, nBSC);
    add_bf16_kernel<<<(n4 + 255) / 256, 256, 0, stream>>>(f_out, pos, b_mlp, n4);

    // ---------------- encoder ----------------
    for (int i = 0; i < 6; ++i) {
        gemmb(b_mlp, w_eow + (size_t)i * 384 * 256, eob + i * 384, f_off, MBS, 384, 256, 0);
        gemmb(b_mlp, w_eaw + (size_t)i * 128 * 256, eab + i * 128, f_awl, MBS, 128, 256, 0);
        gemmb(b_out, w_evw + (size_t)i * 256 * 256, evb + i * 256, f_val, MBS, 256, 256, 0);
        deform_kernel<<<MBS, 256, 0, stream>>>(f_off, f_awl, f_val, b_samp);
        gemmb(b_samp, w_eouw + (size_t)i * 256 * 256, eoub + i * 256, f_mlp, MBS, 256, 256, 0);
        ln_res_kernel<<<lnGrid, 256, 0, stream>>>(f_out, f_mlp, el1g + i * 256, el1b + i * 256,
                                                  f_out, b_out, (const float*)nullptr,
                                                  (unsigned short*)nullptr, MBS);
        // full-size FFN (no chunking); b_hs aliases f_off/f_awl (dead here)
        gemmb(b_out, w_ef1 + (size_t)i * 1024 * 256, ef1b + i * 1024, b_hs, MBS, 1024, 256, 1);
        gemmb(b_hs, w_ef2 + (size_t)i * 256 * 1024, ef2b + i * 256, f_val, MBS, 256, 1024, 0);
        // ln2 also emits bf16(state + pos) for the next layer (lvl_pos after last layer)
        ln_res_kernel<<<lnGrid, 256, 0, stream>>>(f_out, f_val, el2g + i * 256, el2b + i * 256,
                                                  f_out, b_out, (i < 5 ? pos : lvl_pos),
                                                  b_mlp, MBS);
    }

    // ---------------- decoder ----------------
    hipMemcpyAsync(d_q, tgt, 40960 * sizeof(float), hipMemcpyDeviceToDevice, stream);

    for (int i = 0; i < 6; ++i) {
        const float* siw = dsiw + (size_t)i * 768 * 256;
        const float* sib = dsib + (size_t)i * 768;
        add_kernel<<<(dn4 + 255) / 256, 256, 0, stream>>>(d_q, query_pos, d_qk, dn4);
        gemms(d_qk, siw, sib, d_qkp, 160, 512, 256, 0);            // packed Q|K
        gemms(d_q,  siw + 512 * 256, sib + 512, d_sv, 160, 256, 256, 0);
        attn_kernel<<<B_SZ * 8 * (NQ / 4), 256, 0, stream>>>(
            d_qkp, d_qkp + 256, d_sv, d_ao, NQ, NQ, scale, 512, 512);
        gemms(d_ao, dsow + (size_t)i * 256 * 256, dsob + i * 256, d_pr, 160, 256, 256, 0);
        ln_res_kernel<<<40, 256, 0, stream>>>(d_q, d_pr, dl2g + i * 256, dl2b + i * 256,
                                              d_q, (unsigned short*)nullptr,
                                              (const float*)nullptr, (unsigned short*)nullptr, 160);

        const float* cib = dcib + (size_t)i * 768;
        add_kernel<<<(dn4 + 255) / 256, 256, 0, stream>>>(d_q, query_pos, d_qk, dn4);
        gemms(d_qk, dciw + (size_t)i * 768 * 256, cib, d_sq, 160, 256, 256, 0);
        gemmb(b_mlp, w_dciw + (size_t)i * 768 * 256 + 256 * 256, cib + 256,
              f_off, MBS, 256, 256, 0);                                        // cross-K
        gemmb(b_out, w_dciw + (size_t)i * 768 * 256 + 512 * 256, cib + 512,
              f_val, MBS, 256, 256, 0);                                        // cross-V
        xattn_part_kernel<<<dim3(XSPLIT, 16), 256, 0, stream>>>(
            d_sq, f_off, f_val, amask, x_pm, x_pl, x_po, S_TOT, scale);
        xattn_merge_kernel<<<16 * NQ, 64, 0, stream>>>(x_pm, x_pl, x_po, d_ao);
        gemms(d_ao, dcow + (size_t)i * 256 * 256, dcob + i * 256, d_pr, 160, 256, 256, 0);
        ln_res_kernel<<<40, 256, 0, stream>>>(d_q, d_pr, dl1g + i * 256, dl1b + i * 256,
                                              d_q, (unsigned short*)nullptr,
                                              (const float*)nullptr, (unsigned short*)nullptr, 160);

        gemms(d_q, df1w + (size_t)i * 1024 * 256, df1b + i * 1024, d_h, 160, 1024, 256, 1);
        gemms(d_h, df2w + (size_t)i * 256 * 1024, df2b + i * 256, d_pr, 160, 256, 1024, 0);
        ln_res_kernel<<<40, 256, 0, stream>>>(d_q, d_pr, dl3g + i * 256, dl3b + i * 256,
                                              d_q, (unsigned short*)nullptr,
                                              (const float*)nullptr, (unsigned short*)nullptr, 160);
    }

    hipMemcpyAsync(d_out, d_q, 40960 * sizeof(float), hipMemcpyDeviceToDevice, stream);
}

// Round 12
// 4930.030 us; speedup vs baseline: 1.2498x; 1.0113x over previous
//
#include <hip/hip_runtime.h>
#include <cstdint>

#define S_TOT 15795
#define B_SZ 2
#define NQ 80
#define XSPLIT 128
#define XCHUNK 128
#define MP 31616          // 31590 padded to multiple of 128

typedef __attribute__((ext_vector_type(8))) short short8;
typedef __attribute__((ext_vector_type(4))) float f32x4;

__device__ __forceinline__ unsigned short f2bf(float f) {
    unsigned u = __float_as_uint(f);
    unsigned r = u + 0x7fffu + ((u >> 16) & 1u);
    return (unsigned short)(r >> 16);
}

// ---------------------------------------------------------------------------
__global__ __launch_bounds__(256)
void cast_bf16_kernel(const float* __restrict__ x, unsigned short* __restrict__ o, int n4)
{
    int i = blockIdx.x * 256 + threadIdx.x;
    if (i < n4) {
        float4 v = ((const float4*)x)[i];
        ushort4 r;
        r.x = f2bf(v.x); r.y = f2bf(v.y); r.z = f2bf(v.z); r.w = f2bf(v.w);
        ((ushort4*)o)[i] = r;
    }
}

// fused cast of encoder off(384 rows) + aw(128 rows) weights -> [6][512][256] bf16
__global__ __launch_bounds__(256)
void cast_fuse_w_kernel(const float* __restrict__ eow, const float* __restrict__ eaw,
                        unsigned short* __restrict__ o)
{
    int i = blockIdx.x * 256 + threadIdx.x;       // float4 index
    const int n4 = 6 * 512 * 256 / 4;
    if (i < n4) {
        int e = i * 4;
        int layer = e / (512 * 256);
        int rem = e - layer * 512 * 256;
        int row = rem >> 8, col = rem & 255;
        const float* src = (row < 384)
            ? eow + ((size_t)layer * 384 + row) * 256 + col
            : eaw + ((size_t)layer * 128 + (row - 384)) * 256 + col;
        float4 v = *(const float4*)src;
        ushort4 r;
        r.x = f2bf(v.x); r.y = f2bf(v.y); r.z = f2bf(v.z); r.w = f2bf(v.w);
        ((ushort4*)o)[i] = r;
    }
}

// fused bias [6][512] = eob[6][384] | eab[6][128]
__global__ __launch_bounds__(512)
void fuse_bias_kernel(const float* __restrict__ eob, const float* __restrict__ eab,
                      float* __restrict__ o)
{
    int i = blockIdx.x, t = threadIdx.x;
    o[i * 512 + t] = (t < 384) ? eob[i * 384 + t] : eab[i * 128 + (t - 384)];
}

// pack attn mask: mp[k] = 2x uint64, bit q set = blocked. coalesced via LDS.
__global__ __launch_bounds__(256)
void mask_pack_kernel(const unsigned char* __restrict__ mask,
                      unsigned long long* __restrict__ mp, int Lk)
{
    __shared__ unsigned char ml[80][260];
    const int k0 = blockIdx.x * 256;
    const int t = threadIdx.x;
    for (int idx = t; idx < 80 * 256; idx += 256) {
        int q = idx >> 8, kk = idx & 255;
        int kg = k0 + kk;
        ml[q][kk] = (kg < Lk) ? mask[(size_t)q * Lk + kg] : 1;
    }
    __syncthreads();
    int kg = k0 + t;
    if (kg < Lk) {
        unsigned long long lo = 0, hi = 0;
        #pragma unroll
        for (int q = 0; q < 64; ++q)
            lo |= (unsigned long long)(ml[q][t] ? 1u : 0u) << q;
        #pragma unroll
        for (int q = 0; q < 16; ++q)
            hi |= (unsigned long long)(ml[64 + q][t] ? 1u : 0u) << q;
        mp[2 * kg] = lo; mp[2 * kg + 1] = hi;
    }
}

// elementwise add, bf16 out
__global__ __launch_bounds__(256)
void add_bf16_kernel(const float* __restrict__ a, const float* __restrict__ b,
                     unsigned short* __restrict__ o, int n4)
{
    int i = blockIdx.x * 256 + threadIdx.x;
    if (i < n4) {
        float4 av = ((const float4*)a)[i];
        float4 bv = ((const float4*)b)[i];
        ushort4 r;
        r.x = f2bf(av.x + bv.x); r.y = f2bf(av.y + bv.y);
        r.z = f2bf(av.z + bv.z); r.w = f2bf(av.w + bv.w);
        ((ushort4*)o)[i] = r;
    }
}

// ---------------------------------------------------------------------------
// pure-bf16 MFMA GEMM, register-staged DOUBLE-BUFFERED LDS (1 barrier/K-step).
__global__ __launch_bounds__(256)
void gemm_bf16_kernel(const unsigned short* __restrict__ A,
                      const unsigned short* __restrict__ B,
                      const float* __restrict__ bias, void* __restrict__ Yv,
                      int M, int N, int K, int mode)
{
    __shared__ unsigned short As[2][128 * 32];
    __shared__ unsigned short Bs[2][128 * 32];
    const int t = threadIdx.x;
    const int wave = t >> 6, lane = t & 63;
    const int quad = lane >> 4, l16 = lane & 15;
    const int bm0 = blockIdx.y * 128;
    const int bn0 = blockIdx.x * 128;
    const int wm = (wave & 1) * 64;
    const int wn = (wave >> 1) * 64;
    const int srow = t >> 2;
    const int scol = (t & 3) * 8;

    f32x4 acc[4][4] = {};

    const unsigned short* pa0 = A + (size_t)(bm0 + srow) * K + scol;
    const unsigned short* pa1 = pa0 + (size_t)64 * K;
    const unsigned short* pb0 = B + (size_t)(bn0 + srow) * K + scol;
    const unsigned short* pb1 = pb0 + (size_t)64 * K;

    const int nk = K / 32;
    short8 a0 = *(const short8*)(pa0);
    short8 a1 = *(const short8*)(pa1);
    short8 b0 = *(const short8*)(pb0);
    short8 b1 = *(const short8*)(pb1);
    *(short8*)&As[0][srow * 32 + scol] = a0;
    *(short8*)&As[0][(srow + 64) * 32 + scol] = a1;
    *(short8*)&Bs[0][srow * 32 + scol] = b0;
    *(short8*)&Bs[0][(srow + 64) * 32 + scol] = b1;
    __syncthreads();

    for (int kb = 0; kb < nk; ++kb) {
        const int cur = kb & 1, nxt = cur ^ 1;
        const bool more = (kb + 1) < nk;
        if (more) {
            const int k0 = (kb + 1) * 32;
            a0 = *(const short8*)(pa0 + k0);
            a1 = *(const short8*)(pa1 + k0);
            b0 = *(const short8*)(pb0 + k0);
            b1 = *(const short8*)(pb1 + k0);
        }

        short8 af[4], bf[4];
        #pragma unroll
        for (int im = 0; im < 4; ++im)
            af[im] = *(const short8*)&As[cur][(wm + im * 16 + l16) * 32 + quad * 8];
        #pragma unroll
        for (int in = 0; in < 4; ++in)
            bf[in] = *(const short8*)&Bs[cur][(wn + in * 16 + l16) * 32 + quad * 8];
        #pragma unroll
        for (int im = 0; im < 4; ++im)
            #pragma unroll
            for (int in = 0; in < 4; ++in)
                acc[im][in] = __builtin_amdgcn_mfma_f32_16x16x32_bf16(
                    af[im], bf[in], acc[im][in], 0, 0, 0);

        if (more) {
            *(short8*)&As[nxt][srow * 32 + scol] = a0;
            *(short8*)&As[nxt][(srow + 64) * 32 + scol] = a1;
            *(short8*)&Bs[nxt][srow * 32 + scol] = b0;
            *(short8*)&Bs[nxt][(srow + 64) * 32 + scol] = b1;
        }
        __syncthreads();
    }

    #pragma unroll
    for (int im = 0; im < 4; ++im) {
        const int gm0 = bm0 + wm + im * 16 + quad * 4;
        #pragma unroll
        for (int in = 0; in < 4; ++in) {
            const int gn = bn0 + wn + in * 16 + l16;
            const float bv = bias[gn];
            #pragma unroll
            for (int r = 0; r < 4; ++r) {
                int row = gm0 + r;
                if (row < M) {
                    float o = acc[im][in][r] + bv;
                    if (mode == 0) {
                        ((float*)Yv)[(size_t)row * N + gn] = o;
                    } else {
                        if (mode == 1) o = fmaxf(o, 0.f);
                        ((unsigned short*)Yv)[(size_t)row * N + gn] = f2bf(o);
                    }
                }
            }
        }
    }
}

// ---------------------------------------------------------------------------
// fp32 GEMM for small decoder matrices; optional elementwise A-add (X + Xadd).
__global__ __launch_bounds__(256)
void gemm_bias_kernel(const float* __restrict__ X, const float* __restrict__ Xadd,
                      const float* __restrict__ W,
                      const float* __restrict__ bias, float* __restrict__ Y,
                      int M, int N, int K, int relu)
{
    __shared__ float Xs[16][68];
    __shared__ float Ws[16][68];
    const int bm0 = blockIdx.y * 64;
    const int bn0 = blockIdx.x * 64;
    const int t = threadIdx.x;
    const int tx = t & 15, ty = t >> 4;
    const int lr = t >> 2;
    const int lk = (t & 3) << 2;
    float acc[4][4] = {};
    const int xr = bm0 + lr;
    const int wr = bn0 + lr;
    const float* xp = X + (size_t)xr * K + lk;
    const float* xap = Xadd ? Xadd + (size_t)xr * K + lk : nullptr;
    const float* wp = W + (size_t)wr * K + lk;
    for (int k0 = 0; k0 < K; k0 += 16) {
        float4 xv = make_float4(0.f, 0.f, 0.f, 0.f);
        if (xr < M) {
            xv = *(const float4*)(xp + k0);
            if (xap) {
                float4 av = *(const float4*)(xap + k0);
                xv.x += av.x; xv.y += av.y; xv.z += av.z; xv.w += av.w;
            }
        }
        float4 wv = make_float4(0.f, 0.f, 0.f, 0.f);
        if (wr < N) wv = *(const float4*)(wp + k0);
        Xs[lk + 0][lr] = xv.x; Xs[lk + 1][lr] = xv.y;
        Xs[lk + 2][lr] = xv.z; Xs[lk + 3][lr] = xv.w;
        Ws[lk + 0][lr] = wv.x; Ws[lk + 1][lr] = wv.y;
        Ws[lk + 2][lr] = wv.z; Ws[lk + 3][lr] = wv.w;
        __syncthreads();
        #pragma unroll
        for (int k = 0; k < 16; ++k) {
            float a0 = Xs[k][ty * 4 + 0], a1 = Xs[k][ty * 4 + 1];
            float a2 = Xs[k][ty * 4 + 2], a3 = Xs[k][ty * 4 + 3];
            float b0 = Ws[k][tx * 4 + 0], b1 = Ws[k][tx * 4 + 1];
            float b2 = Ws[k][tx * 4 + 2], b3 = Ws[k][tx * 4 + 3];
            acc[0][0] += a0 * b0; acc[0][1] += a0 * b1; acc[0][2] += a0 * b2; acc[0][3] += a0 * b3;
            acc[1][0] += a1 * b0; acc[1][1] += a1 * b1; acc[1][2] += a1 * b2; acc[1][3] += a1 * b3;
            acc[2][0] += a2 * b0; acc[2][1] += a2 * b1; acc[2][2] += a2 * b2; acc[2][3] += a2 * b3;
            acc[3][0] += a3 * b0; acc[3][1] += a3 * b1; acc[3][2] += a3 * b2; acc[3][3] += a3 * b3;
        }
        __syncthreads();
    }
    const int c0 = bn0 + tx * 4;
    float4 bv = *(const float4*)(bias + c0);
    #pragma unroll
    for (int i = 0; i < 4; ++i) {
        int r = bm0 + ty * 4 + i;
        if (r >= M) continue;
        float4 o;
        o.x = acc[i][0] + bv.x; o.y = acc[i][1] + bv.y;
        o.z = acc[i][2] + bv.z; o.w = acc[i][3] + bv.w;
        if (relu) {
            o.x = fmaxf(o.x, 0.f); o.y = fmaxf(o.y, 0.f);
            o.z = fmaxf(o.z, 0.f); o.w = fmaxf(o.w, 0.f);
        }
        *(float4*)(Y + (size_t)r * N + c0) = o;
    }
}

// ---------------------------------------------------------------------------
// LayerNorm(X + R)*g + b -> fp32 O, optional bf16 Ob, optional bf16 (O+Padd).
__global__ __launch_bounds__(256)
void ln_res_kernel(const float* __restrict__ X, const float* __restrict__ R,
                   const float* __restrict__ g, const float* __restrict__ bta,
                   float* __restrict__ O, unsigned short* __restrict__ Ob,
                   const float* __restrict__ Padd, unsigned short* __restrict__ Oadd,
                   int nrows)
{
    const int row = blockIdx.x * 4 + (threadIdx.x >> 6);
    if (row >= nrows) return;
    const int t = threadIdx.x & 63;
    const float* x = X + (size_t)row * 256;
    const float* r = R + (size_t)row * 256;
    float v[4];
    float s = 0.f;
    #pragma unroll
    for (int i = 0; i < 4; ++i) { int c = t + 64 * i; v[i] = x[c] + r[c]; s += v[i]; }
    #pragma unroll
    for (int off = 32; off >= 1; off >>= 1) s += __shfl_xor(s, off, 64);
    float mu = s * (1.f / 256.f);
    float s2 = 0.f;
    #pragma unroll
    for (int i = 0; i < 4; ++i) { float d = v[i] - mu; s2 += d * d; }
    #pragma unroll
    for (int off = 32; off >= 1; off >>= 1) s2 += __shfl_xor(s2, off, 64);
    float rstd = rsqrtf(s2 * (1.f / 256.f) + 1e-5f);
    #pragma unroll
    for (int i = 0; i < 4; ++i) {
        int c = t + 64 * i;
        float o = (v[i] - mu) * rstd * g[c] + bta[c];
        O[(size_t)row * 256 + c] = o;
        if (Ob) Ob[(size_t)row * 256 + c] = f2bf(o);
        if (Oadd) Oadd[(size_t)row * 256 + c] = f2bf(o + Padd[(size_t)row * 256 + c]);
    }
}

// ---------------------------------------------------------------------------
// 3D deformable attention; offsets+aw-logits packed per token in [512] row.
__global__ __launch_bounds__(256)
void deform_kernel(const float* __restrict__ offaw,
                   const float* __restrict__ value, unsigned short* __restrict__ out)
{
    const int bq = blockIdx.x;
    const int b = bq / S_TOT;
    const int s = bq - b * S_TOT;
    const int t = threadIdx.x;

    __shared__ float aw_sh[128];
    __shared__ float aw_m[8], aw_s[8];
    __shared__ float2 tbl[128][8];
    __shared__ float4 racc[256];

    if (t < 128) aw_sh[t] = offaw[(size_t)bq * 512 + 384 + t];
    __syncthreads();
    if (t < 8) {
        float m = -1e30f;
        #pragma unroll
        for (int i = 0; i < 16; ++i) m = fmaxf(m, aw_sh[t * 16 + i]);
        float su = 0.f;
        #pragma unroll
        for (int i = 0; i < 16; ++i) su += __expf(aw_sh[t * 16 + i] - m);
        aw_m[t] = m; aw_s[t] = su;
    }
    __syncthreads();

    if (t < 128) {
        const int h = t >> 4, lp = t & 15, l = lp >> 2;
        float aw = __expf(aw_sh[t] - aw_m[h]) / aw_s[h];
        int nq_, sq0;
        if (s < 13824)      { nq_ = 24; sq0 = 0; }
        else if (s < 15552) { nq_ = 12; sq0 = 13824; }
        else if (s < 15768) { nq_ = 6;  sq0 = 15552; }
        else                { nq_ = 3;  sq0 = 15768; }
        int tl = s - sq0;
        int iz = tl / (nq_ * nq_);
        int r1 = tl - iz * nq_ * nq_;
        int iy = r1 / nq_;
        int ix = r1 - iy * nq_;
        float invn = 1.f / (float)nq_;
        float rx = (ix + 0.5f) * invn;
        float ry = (iy + 0.5f) * invn;
        float rz = (iz + 0.5f) * invn;

        const int lvl_n[4]  = {24, 12, 6, 3};
        const int lvl_s0[4] = {0, 13824, 15552, 15768};
        const int nl = lvl_n[l];
        const int s0l = lvl_s0[l];
        const float* op = offaw + (size_t)bq * 512 + t * 3;
        float x = rx * nl + op[0] - 0.5f;
        float y = ry * nl + op[1] - 0.5f;
        float z = rz * nl + op[2] - 0.5f;
        float fx = floorf(x), fy = floorf(y), fz = floorf(z);
        int x0 = (int)fx, y0 = (int)fy, z0 = (int)fz;
        float wx1 = x - fx, wx0 = 1.f - wx1;
        float wy1 = y - fy, wy0 = 1.f - wy1;
        float wz1 = z - fz, wz0 = 1.f - wz1;
        int xc0 = min(max(x0, 0), nl - 1), xc1 = min(max(x0 + 1, 0), nl - 1);
        int yc0 = min(max(y0, 0), nl - 1), yc1 = min(max(y0 + 1, 0), nl - 1);
        int zc0 = min(max(z0, 0), nl - 1), zc1 = min(max(z0 + 1, 0), nl - 1);
        bool ox0 = (x0 >= 0) && (x0 < nl);
        bool ox1 = (x0 + 1 >= 0) && (x0 + 1 < nl);
        bool oy0 = (y0 >= 0) && (y0 < nl), oy1 = (y0 + 1 >= 0) && (y0 + 1 < nl);
        bool oz0 = (z0 >= 0) && (z0 < nl), oz1 = (z0 + 1 >= 0) && (z0 + 1 < nl);
        int base = b * S_TOT + s0l;
        #pragma unroll
        for (int c = 0; c < 8; ++c) {
            int dx = c & 1, dy = (c >> 1) & 1, dz = c >> 2;
            float w = (dx ? wx1 : wx0) * (dy ? wy1 : wy0) * (dz ? wz1 : wz0);
            bool ok = (dx ? ox1 : ox0) && (dy ? oy1 : oy0) && (dz ? oz1 : oz0);
            int xi = dx ? xc1 : xc0;
            int yi = dy ? yc1 : yc0;
            int zi = dz ? zc1 : zc0;
            int elem = ((base + (zi * nl + yi) * nl + xi) * 8 + h) * 32;
            tbl[t][c] = make_float2(ok ? w * aw : 0.f, __int_as_float(elem));
        }
    }
    __syncthreads();

    const int c4 = t & 7, lpg = (t >> 3) & 3, h2 = t >> 5;
    float4 acc = make_float4(0.f, 0.f, 0.f, 0.f);
    #pragma unroll
    for (int j = 0; j < 4; ++j) {
        const float2* row = tbl[h2 * 16 + lpg * 4 + j];
        #pragma unroll
        for (int c = 0; c < 8; ++c) {
            float2 e = row[c];
            const float4 v = *(const float4*)(value + (size_t)__float_as_int(e.y) + c4 * 4);
            acc.x += e.x * v.x; acc.y += e.x * v.y;
            acc.z += e.x * v.z; acc.w += e.x * v.w;
        }
    }
    racc[t] = acc;
    __syncthreads();
    if (lpg == 0) {
        float4 a = racc[t];
        #pragma unroll
        for (int gg = 1; gg < 4; ++gg) {
            float4 o = racc[t + gg * 8];
            a.x += o.x; a.y += o.y; a.z += o.z; a.w += o.w;
        }
        ushort4 r;
        r.x = f2bf(a.x); r.y = f2bf(a.y); r.z = f2bf(a.z); r.w = f2bf(a.w);
        *(ushort4*)(out + (size_t)bq * 256 + h2 * 32 + c4 * 4) = r;
    }
}

// ---------------------------------------------------------------------------
// small multi-head attention (decoder self-attn, Lk=80), online softmax.
__global__ __launch_bounds__(256)
void attn_kernel(const float* __restrict__ Q, const float* __restrict__ K,
                 const float* __restrict__ V, float* __restrict__ O,
                 int Lq, int Lk, float scale, int ldq, int ldk)
{
    const int nqc = (Lq + 3) >> 2;
    const int blk = blockIdx.x;
    const int qc = blk % nqc;
    const int bh = blk / nqc;
    const int h = bh & 7;
    const int b = bh >> 3;
    const int qi0 = qc * 4;
    const int t = threadIdx.x;
    const int c = t & 31, g = t >> 5;

    float qv[4];
    #pragma unroll
    for (int j = 0; j < 4; ++j)
        qv[j] = Q[((size_t)(b * Lq + qi0 + j)) * ldq + h * 32 + c];

    float m[4], l[4], acc[4];
    #pragma unroll
    for (int j = 0; j < 4; ++j) { m[j] = -1e30f; l[j] = 0.f; acc[j] = 0.f; }

    for (int k = g; k < Lk; k += 8) {
        float kv = K[((size_t)(b * Lk + k)) * ldk + h * 32 + c];
        float vv = V[((size_t)(b * Lk + k)) * 256 + h * 32 + c];
        #pragma unroll
        for (int j = 0; j < 4; ++j) {
            float p = qv[j] * kv;
            p += __shfl_xor(p, 16, 32);
            p += __shfl_xor(p, 8, 32);
            p += __shfl_xor(p, 4, 32);
            p += __shfl_xor(p, 2, 32);
            p += __shfl_xor(p, 1, 32);
            float sc = p * scale;
            float mn = fmaxf(m[j], sc);
            float fo = __expf(m[j] - mn);
            float w = __expf(sc - mn);
            l[j] = l[j] * fo + w;
            acc[j] = acc[j] * fo + w * vv;
            m[j] = mn;
        }
    }
    __shared__ float sm[8][4], sl[8][4], sacc[8][4][32];
    if (c == 0) {
        #pragma unroll
        for (int j = 0; j < 4; ++j) { sm[g][j] = m[j]; sl[g][j] = l[j]; }
    }
    #pragma unroll
    for (int j = 0; j < 4; ++j) sacc[g][j][c] = acc[j];
    __syncthreads();
    if (g == 0) {
        #pragma unroll
        for (int j = 0; j < 4; ++j) {
            float M = -1e30f;
            #pragma unroll
            for (int i = 0; i < 8; ++i) M = fmaxf(M, sm[i][j]);
            float L = 0.f, o = 0.f;
            #pragma unroll
            for (int i = 0; i < 8; ++i) {
                float e = __expf(sm[i][j] - M);
                L += sl[i][j] * e;
                o += sacc[i][j][c] * e;
            }
            O[((size_t)(b * Lq + qi0 + j)) * 256 + h * 32 + c] = o / L;
        }
    }
}

// ---------------------------------------------------------------------------
// split-K flash cross-attention, phase 1; packed-bitmask variant.
__global__ __launch_bounds__(256)
void xattn_part_kernel(const float* __restrict__ Q, const float* __restrict__ K,
                       const float* __restrict__ V,
                       const unsigned long long* __restrict__ mp,
                       float* __restrict__ pm, float* __restrict__ pl,
                       float* __restrict__ po, int Lk, float scale)
{
    const int split = blockIdx.x;
    const int bh = blockIdx.y;
    const int b = bh >> 3, h = bh & 7;
    const int t = threadIdx.x;
    const int kk = t & 31;
    const int qg = t >> 5;

    __shared__ float Qs[80 * 32];
    __shared__ float Ks[32][33];
    __shared__ float Vs[32][33];
    __shared__ float Ps[80][33];

    for (int i = t; i < 2560; i += 256) {
        int q = i >> 5, c = i & 31;
        Qs[i] = Q[((size_t)(b * NQ + q)) * 256 + h * 32 + c];
    }

    float m[10], l[10], acc[10];
    #pragma unroll
    for (int i = 0; i < 10; ++i) { m[i] = -1e9f; l[i] = 0.f; acc[i] = 0.f; }

    const int k_base = split * XCHUNK;
    for (int k0 = k_base; k0 < k_base + XCHUNK; k0 += 32) {
        __syncthreads();
        {
            int key = t >> 3, c4 = (t & 7) * 4;
            int kg = k0 + key;
            float4 kv = make_float4(0.f, 0.f, 0.f, 0.f);
            float4 vv = make_float4(0.f, 0.f, 0.f, 0.f);
            if (kg < Lk) {
                size_t go = ((size_t)(b * Lk + kg)) * 256 + h * 32 + c4;
                kv = *(const float4*)(K + go);
                vv = *(const float4*)(V + go);
            }
            Ks[key][c4 + 0] = kv.x; Ks[key][c4 + 1] = kv.y;
            Ks[key][c4 + 2] = kv.z; Ks[key][c4 + 3] = kv.w;
            Vs[key][c4 + 0] = vv.x; Vs[key][c4 + 1] = vv.y;
            Vs[key][c4 + 2] = vv.z; Vs[key][c4 + 3] = vv.w;
        }
        __syncthreads();

        float s[10];
        #pragma unroll
        for (int i = 0; i < 10; ++i) s[i] = 0.f;
        #pragma unroll 8
        for (int c = 0; c < 32; ++c) {
            float kv = Ks[kk][c];
            #pragma unroll
            for (int i = 0; i < 10; ++i) s[i] += Qs[(qg * 10 + i) * 32 + c] * kv;
        }
        const int kg = k0 + kk;
        const bool valid = kg < Lk;
        unsigned long long mlo = 0xFFFFFFFFFFFFFFFFULL, mhi = 0xFFFFFFFFFFFFFFFFULL;
        if (valid) { mlo = mp[2 * kg]; mhi = mp[2 * kg + 1]; }
        float alpha[10];
        #pragma unroll
        for (int i = 0; i < 10; ++i) {
            const int q = qg * 10 + i;
            bool blocked = (q < 64) ? ((mlo >> q) & 1ULL) : ((mhi >> (q - 64)) & 1ULL);
            float sc = (valid && !blocked) ? s[i] * scale : -1e9f;
            float rm = sc;
            rm = fmaxf(rm, __shfl_xor(rm, 16, 32));
            rm = fmaxf(rm, __shfl_xor(rm, 8, 32));
            rm = fmaxf(rm, __shfl_xor(rm, 4, 32));
            rm = fmaxf(rm, __shfl_xor(rm, 2, 32));
            rm = fmaxf(rm, __shfl_xor(rm, 1, 32));
            float mn = fmaxf(m[i], rm);
            alpha[i] = __expf(m[i] - mn);
            float p = valid ? __expf(sc - mn) : 0.f;
            float ps = p;
            ps += __shfl_xor(ps, 16, 32);
            ps += __shfl_xor(ps, 8, 32);
            ps += __shfl_xor(ps, 4, 32);
            ps += __shfl_xor(ps, 2, 32);
            ps += __shfl_xor(ps, 1, 32);
            l[i] = l[i] * alpha[i] + ps;
            m[i] = mn;
            Ps[q][kk] = p;
        }
        __syncthreads();

        #pragma unroll
        for (int i = 0; i < 10; ++i) acc[i] *= alpha[i];
        #pragma unroll 8
        for (int kj = 0; kj < 32; ++kj) {
            float v = Vs[kj][kk];
            #pragma unroll
            for (int i = 0; i < 10; ++i) acc[i] += Ps[qg * 10 + i][kj] * v;
        }
    }

    const size_t base = ((size_t)bh * XSPLIT + split) * NQ;
    #pragma unroll
    for (int i = 0; i < 10; ++i) {
        const int q = qg * 10 + i;
        if (kk == 0) { pm[base + q] = m[i]; pl[base + q] = l[i]; }
        po[(base + q) * 32 + kk] = acc[i];
    }
}

// phase 2: merge XSPLIT partials per (b,h,q) -> O[B,NQ,256]
__global__ __launch_bounds__(64)
void xattn_merge_kernel(const float* __restrict__ pm, const float* __restrict__ pl,
                        const float* __restrict__ po, float* __restrict__ O)
{
    const int idx = blockIdx.x;
    const int bh = idx / NQ, q = idx - bh * NQ;
    const int b = bh >> 3, h = bh & 7;
    const int tt = threadIdx.x;
    if (tt >= 32) return;
    const int c = tt;
    float M = -1e30f;
    for (int s = 0; s < XSPLIT; ++s)
        M = fmaxf(M, pm[((size_t)bh * XSPLIT + s) * NQ + q]);
    float L = 0.f, o = 0.f;
    for (int s = 0; s < XSPLIT; ++s) {
        size_t base = ((size_t)bh * XSPLIT + s) * NQ + q;
        float e = __expf(pm[base] - M);
        L += pl[base] * e;
        o += po[base * 32 + c] * e;
    }
    O[((size_t)(b * NQ + q)) * 256 + h * 32 + c] = o / L;
}

// ---------------------------------------------------------------------------
extern "C" void kernel_launch(void* const* d_in, const int* in_sizes, int n_in,
                              void* d_out, int out_size, void* d_ws, size_t ws_size,
                              hipStream_t stream)
{
    const float* src       = (const float*)d_in[0];
    const float* pos       = (const float*)d_in[1];
    const float* lvl_pos   = (const float*)d_in[2];
    const float* tgt       = (const float*)d_in[3];
    const float* query_pos = (const float*)d_in[4];
    const float* eow  = (const float*)d_in[6];
    const float* eob  = (const float*)d_in[7];
    const float* eaw  = (const float*)d_in[8];
    const float* eab  = (const float*)d_in[9];
    const float* evw  = (const float*)d_in[10];
    const float* evb  = (const float*)d_in[11];
    const float* eouw = (const float*)d_in[12];
    const float* eoub = (const float*)d_in[13];
    const float* el1g = (const float*)d_in[14];
    const float* el1b = (const float*)d_in[15];
    const float* ef1w = (const float*)d_in[16];
    const float* ef1b = (const float*)d_in[17];
    const float* ef2w = (const float*)d_in[18];
    const float* ef2b = (const float*)d_in[19];
    const float* el2g = (const float*)d_in[20];
    const float* el2b = (const float*)d_in[21];
    const float* dsiw = (const float*)d_in[22];
    const float* dsib = (const float*)d_in[23];
    const float* dsow = (const float*)d_in[24];
    const float* dsob = (const float*)d_in[25];
    const float* dciw = (const float*)d_in[26];
    const float* dcib = (const float*)d_in[27];
    const float* dcow = (const float*)d_in[28];
    const float* dcob = (const float*)d_in[29];
    const float* dl1g = (const float*)d_in[30];
    const float* dl1b = (const float*)d_in[31];
    const float* dl2g = (const float*)d_in[32];
    const float* dl2b = (const float*)d_in[33];
    const float* dl3g = (const float*)d_in[34];
    const float* dl3b = (const float*)d_in[35];
    const float* df1w = (const float*)d_in[36];
    const float* df1b = (const float*)d_in[37];
    const float* df2w = (const float*)d_in[38];
    const float* df2b = (const float*)d_in[39];
    const unsigned char* amask = (const unsigned char*)d_in[40];

    const int MBS = B_SZ * S_TOT;                  // 31590
    const size_t nBSC = (size_t)MBS * 256;
    const size_t nP   = (size_t)MP * 256;
    const size_t nFFA = (size_t)MBS * 512 + 16384; // packed off|aw ; aliased by b_hs

    float* ws = (float*)d_ws;
    float* f_out = ws; ws += nP;                   // encoder state / memory (fp32)
    float* f_mlp = ws; ws += nP;                   // proj output for residual
    float* f_ffa = ws; ws += nFFA;                 // f_offaw ; aliased by b_hs
    float* f_offaw = f_ffa;                        // [MBS,512] enc off|aw ; dec cross-K [MBS,256]
    float* f_val = ws; ws += nP;                   // enc value / fc2-out ; dec cross-V
    float* d_q   = ws; ws += 40960;
    float* d_qkp = ws; ws += 81920;                // packed self-attn Q|K [160,512]
    float* d_sq  = ws; ws += 40960;
    float* d_sv  = ws; ws += 40960;
    float* d_ao  = ws; ws += 40960;
    float* d_pr  = ws; ws += 40960;
    float* d_h   = ws; ws += 163840;
    float* x_pm  = ws; ws += (size_t)16 * XSPLIT * NQ;
    float* x_pl  = ws; ws += (size_t)16 * XSPLIT * NQ;
    float* x_po  = ws; ws += (size_t)16 * XSPLIT * NQ * 32;
    unsigned long long* x_mp = (unsigned long long*)ws; ws += 2 * 16384;  // packed mask
    float* f_fb  = ws; ws += 6 * 512;              // fused enc off|aw bias

    unsigned short* bws = (unsigned short*)ws;
    unsigned short* b_mlp  = bws; bws += nP;            // bf16(state+pos)/dec memory+lvl_pos
    unsigned short* b_out  = bws; bws += nP;            // bf16 encoder state
    unsigned short* w_eoaw = bws; bws += (size_t)6 * 512 * 256;   // fused off|aw weights
    unsigned short* w_evw  = bws; bws += (size_t)6 * 256 * 256;
    unsigned short* w_eouw = bws; bws += (size_t)6 * 256 * 256;
    unsigned short* w_ef1  = bws; bws += (size_t)6 * 1024 * 256;
    unsigned short* w_ef2  = bws; bws += (size_t)6 * 256 * 1024;
    unsigned short* w_dciw = bws; bws += (size_t)6 * 768 * 256;

    // aliases (disjoint lifetimes):
    unsigned short* b_hs   = (unsigned short*)f_ffa;   // fc1 out (MP*1024 bf16)
    unsigned short* b_samp = b_mlp;                    // deform out (MBS*256 bf16)

    auto gemmb = [&](const unsigned short* A, const unsigned short* W, const float* bb,
                     void* Y, int M, int N, int K, int mode) {
        dim3 grid(N / 128, (M + 127) / 128);
        gemm_bf16_kernel<<<grid, dim3(256), 0, stream>>>(A, W, bb, Y, M, N, K, mode);
    };
    auto gemms = [&](const float* X, const float* Xadd, const float* W, const float* bb,
                     float* Y, int M, int N, int K, int relu) {
        dim3 grid(N / 64, (M + 63) / 64);
        gemm_bias_kernel<<<grid, dim3(256), 0, stream>>>(X, Xadd, W, bb, Y, M, N, K, relu);
    };
    auto cast = [&](const float* x, unsigned short* o, size_t n) {
        int n4c = (int)(n / 4);
        cast_bf16_kernel<<<(n4c + 255) / 256, 256, 0, stream>>>(x, o, n4c);
    };

    const int n4 = (int)(nBSC / 4);
    const float scale = 0.17677669529663687f;
    const int lnGrid = (MBS + 3) / 4;

    // one-time prep
    {
        const int nf4 = 6 * 512 * 256 / 4;
        cast_fuse_w_kernel<<<(nf4 + 255) / 256, 256, 0, stream>>>(eow, eaw, w_eoaw);
        fuse_bias_kernel<<<6, 512, 0, stream>>>(eob, eab, f_fb);
        mask_pack_kernel<<<(S_TOT + 255) / 256, 256, 0, stream>>>(amask, x_mp, S_TOT);
    }
    cast(evw,  w_evw,  (size_t)6 * 256 * 256);
    cast(eouw, w_eouw, (size_t)6 * 256 * 256);
    cast(ef1w, w_ef1,  (size_t)6 * 1024 * 256);
    cast(ef2w, w_ef2,  (size_t)6 * 256 * 1024);
    cast(dciw, w_dciw, (size_t)6 * 768 * 256);

    hipMemcpyAsync(f_out, src, nBSC * sizeof(float), hipMemcpyDeviceToDevice, stream);
    cast(src, b_out, nBSC);
    add_bf16_kernel<<<(n4 + 255) / 256, 256, 0, stream>>>(f_out, pos, b_mlp, n4);

    // ---------------- encoder ----------------
    for (int i = 0; i < 6; ++i) {
        gemmb(b_mlp, w_eoaw + (size_t)i * 512 * 256, f_fb + i * 512, f_offaw, MBS, 512, 256, 0);
        gemmb(b_out, w_evw + (size_t)i * 256 * 256, evb + i * 256, f_val, MBS, 256, 256, 0);
        deform_kernel<<<MBS, 256, 0, stream>>>(f_offaw, f_val, b_samp);
        gemmb(b_samp, w_eouw + (size_t)i * 256 * 256, eoub + i * 256, f_mlp, MBS, 256, 256, 0);
        ln_res_kernel<<<lnGrid, 256, 0, stream>>>(f_out, f_mlp, el1g + i * 256, el1b + i * 256,
                                                  f_out, b_out, (const float*)nullptr,
                                                  (unsigned short*)nullptr, MBS);
        gemmb(b_out, w_ef1 + (size_t)i * 1024 * 256, ef1b + i * 1024, b_hs, MBS, 1024, 256, 1);
        gemmb(b_hs, w_ef2 + (size_t)i * 256 * 1024, ef2b + i * 256, f_val, MBS, 256, 1024, 0);
        ln_res_kernel<<<lnGrid, 256, 0, stream>>>(f_out, f_val, el2g + i * 256, el2b + i * 256,
                                                  f_out, b_out, (i < 5 ? pos : lvl_pos),
                                                  b_mlp, MBS);
    }

    // ---------------- decoder ----------------
    hipMemcpyAsync(d_q, tgt, 40960 * sizeof(float), hipMemcpyDeviceToDevice, stream);

    for (int i = 0; i < 6; ++i) {
        const float* siw = dsiw + (size_t)i * 768 * 256;
        const float* sib = dsib + (size_t)i * 768;
        gemms(d_q, query_pos, siw, sib, d_qkp, 160, 512, 256, 0);        // packed Q|K
        gemms(d_q, nullptr, siw + 512 * 256, sib + 512, d_sv, 160, 256, 256, 0);
        attn_kernel<<<B_SZ * 8 * (NQ / 4), 256, 0, stream>>>(
            d_qkp, d_qkp + 256, d_sv, d_ao, NQ, NQ, scale, 512, 512);
        gemms(d_ao, nullptr, dsow + (size_t)i * 256 * 256, dsob + i * 256, d_pr, 160, 256, 256, 0);
        ln_res_kernel<<<40, 256, 0, stream>>>(d_q, d_pr, dl2g + i * 256, dl2b + i * 256,
                                              d_q, (unsigned short*)nullptr,
                                              (const float*)nullptr, (unsigned short*)nullptr, 160);

        const float* cib = dcib + (size_t)i * 768;
        gemms(d_q, query_pos, dciw + (size_t)i * 768 * 256, cib, d_sq, 160, 256, 256, 0);
        gemmb(b_mlp, w_dciw + (size_t)i * 768 * 256 + 256 * 256, cib + 256,
              f_offaw, MBS, 256, 256, 0);                                      // cross-K
        gemmb(b_out, w_dciw + (size_t)i * 768 * 256 + 512 * 256, cib + 512,
              f_val, MBS, 256, 256, 0);                                        // cross-V
        xattn_part_kernel<<<dim3(XSPLIT, 16), 256, 0, stream>>>(
            d_sq, f_offaw, f_val, x_mp, x_pm, x_pl, x_po, S_TOT, scale);
        xattn_merge_kernel<<<16 * NQ, 64, 0, stream>>>(x_pm, x_pl, x_po, d_ao);
        gemms(d_ao, nullptr, dcow + (size_t)i * 256 * 256, dcob + i * 256, d_pr, 160, 256, 256, 0);
        ln_res_kernel<<<40, 256, 0, stream>>>(d_q, d_pr, dl1g + i * 256, dl1b + i * 256,
                                              d_q, (unsigned short*)nullptr,
                                              (const float*)nullptr, (unsigned short*)nullptr, 160);

        gemms(d_q, nullptr, df1w + (size_t)i * 1024 * 256, df1b + i * 1024, d_h, 160, 1024, 256, 1);
        gemms(d_h, nullptr, df2w + (size_t)i * 256 * 1024, df2b + i * 256, d_pr, 160, 256, 1024, 0);
        ln_res_kernel<<<40, 256, 0, stream>>>(d_q, d_pr, dl3g + i * 256, dl3b + i * 256,
                                              d_q, (unsigned short*)nullptr,
                                              (const float*)nullptr, (unsigned short*)nullptr, 160);
    }

    hipMemcpyAsync(d_out, d_q, 40960 * sizeof(float), hipMemcpyDeviceToDevice, stream);
}